// Round 8
// baseline (722.443 us; speedup 1.0000x reference)
//
#include <hip/hip_runtime.h>
#include <hip/hip_bf16.h>
#include <math.h>

// ---------------------------------------------------------------------------
// GuoCapSAREncoder round 8:
//  - conv2: 2-output-row blocks -> grid 1216 (4.75/CU), LDS 34.3 KB (4
//    resident blocks/CU) to fix latency starvation (was 640 blocks, occ 13.7%).
//  - routing: all 3 iterations fused into ONE kernel (k_route_all, 64 blocks);
//    b_log in registers, v in LDS, uhT re-read from L2.
//  - conv1-MFMA / convcaps / uhat unchanged from round 7.
// ---------------------------------------------------------------------------

#define EPSF 1e-8f

typedef __bf16 bf16x8 __attribute__((ext_vector_type(8)));
typedef __bf16 bf16x4 __attribute__((ext_vector_type(4)));
typedef float floatx4 __attribute__((ext_vector_type(4)));

// ---- weight transposes ----------------------------------------------------
// w1[oc][81] fp32 -> w1b[12 kt][128 oc][8 j] bf16, k = kt*8+j padded to 96
__global__ __launch_bounds__(256) void k_t_w1b(const float* __restrict__ w1, __bf16* __restrict__ w1b) {
    int i = blockIdx.x * 256 + threadIdx.x;          // 12*128*8 = 12288
    if (i >= 12288) return;
    int kt = i >> 10, oc = (i >> 3) & 127, j = i & 7;
    int k = kt * 8 + j;
    w1b[i] = (__bf16)(k < 81 ? w1[oc * 81 + k] : 0.f);
}

__global__ __launch_bounds__(256) void k_t_w2b(const float* __restrict__ w2, __bf16* __restrict__ w2b) {
    int j = blockIdx.x * 256 + threadIdx.x;          // 204800
    if (j >= 204800) return;
    int khw = j / 8192, r2 = j & 8191;
    int oc = r2 >> 7, ic = r2 & 127;
    w2b[j] = (__bf16)w2[(oc * 128 + ic) * 25 + khw];
}

__global__ __launch_bounds__(256) void k_t_wcb(const float* __restrict__ wc, __bf16* __restrict__ wcb) {
    int j = blockIdx.x * 256 + threadIdx.x;          // 524288
    if (j >= 524288) return;
    int khw = j / 8192, r2 = j & 8191;
    int oc = r2 >> 6, ic = r2 & 63;
    wcb[j] = (__bf16)wc[(oc * 64 + ic) * 64 + khw];
}

// ---- conv1 9x9 + ReLU + maxpool2 via MFMA -> h1n NHWC bf16 [b][42][42][128]
__global__ __launch_bounds__(256, 3) void k_conv1_mfma(const float* __restrict__ x,
                                                       const __bf16* __restrict__ w1b,
                                                       const float* __restrict__ b1,
                                                       __bf16* __restrict__ h1n) {
    __shared__ float xs[960];                        // 10 rows x 92 fp32 (+pad)
    __shared__ __bf16 Bl[18432];                     // 12kt x 2row x 96pos x 8j
    int py = blockIdx.x, ocg = blockIdx.y, b = blockIdx.z;
    int t = threadIdx.x;
    int lane = t & 63, w = t >> 6;
    int cc = lane & 15, q = lane >> 4;

    const float* xb = x + (size_t)b * 8464 + 2 * py * 92;
    for (int j = t; j < 920; j += 256) xs[j] = xb[j];

    int ocA = ocg * 64 + w * 16 + cc;
    bf16x8 af[3];
#pragma unroll
    for (int ks = 0; ks < 3; ++ks)
        af[ks] = *(const bf16x8*)(w1b + ((ks * 4 + q) * 128 + ocA) * 8);

    __syncthreads();

    if (t < 192) {
        int row = t / 96, pos = t - (t / 96) * 96;
        int sbase = row * 92 + pos;
        bool pvalid = pos < 84;
#pragma unroll
        for (int kt = 0; kt < 12; ++kt) {
            bf16x8 pk;
#pragma unroll
            for (int j = 0; j < 8; ++j) {
                int k = kt * 8 + j;
                int kh = k / 9, kw = k - kh * 9;
                float v = (pvalid && k < 81) ? xs[sbase + kh * 92 + kw] : 0.f;
                pk[j] = (__bf16)v;
            }
            *(bf16x8*)(Bl + ((kt * 2 + row) * 96 + pos) * 8) = pk;
        }
    }
    __syncthreads();

    floatx4 acc[2][6];
    const char* Bb = (const char*)Bl + cc * 16 + q * 3072;
#pragma unroll
    for (int rr = 0; rr < 2; ++rr)
#pragma unroll
        for (int n6 = 0; n6 < 6; ++n6) {
            floatx4 a = (floatx4){0.f, 0.f, 0.f, 0.f};
#pragma unroll
            for (int ks = 0; ks < 3; ++ks) {
                bf16x8 bf = *(const bf16x8*)(Bb + ks * 12288 + rr * 1536 + n6 * 256);
                a = __builtin_amdgcn_mfma_f32_16x16x32_bf16(af[ks], bf, a, 0, 0, 0);
            }
            acc[rr][n6] = a;
        }

    int oc0 = ocg * 64 + w * 16 + q * 4;
    float4 bv = *(const float4*)(b1 + oc0);
    size_t obase = (((size_t)b * 42 + py) * 42) * 128 + oc0;
#pragma unroll
    for (int n6 = 0; n6 < 6; ++n6) {
        bf16x4 pk;
#pragma unroll
        for (int r = 0; r < 4; ++r) {
            float vert = fmaxf(acc[0][n6][r], acc[1][n6][r]);
            float hz = fmaxf(vert, __shfl_xor(vert, 1, 64));
            float pooled = fmaxf(hz + ((const float*)&bv)[r], 0.f);
            pk[r] = (__bf16)pooled;
        }
        if ((cc & 1) == 0) {
            int px = n6 * 8 + (cc >> 1);
            if (px < 42)
                *(bf16x4*)(h1n + obase + (size_t)px * 128) = pk;
        }
    }
}

// ---- conv2 5x5 via MFMA: h1n NHWC bf16 -> h2n NHWC bf16 [b][38][38][64] ---
// 2-output-row blocks: grid (19,64)=1216. LDS 252 pos * 136 B = 34272 B
// (pitch 34 dwords = 2 mod 32 banks, conflict-free; offsets are immediates).
__global__ __launch_bounds__(256, 2) void k_conv2(const __bf16* __restrict__ h1n,
                                                  const __bf16* __restrict__ w2b,
                                                  const float* __restrict__ b2,
                                                  __bf16* __restrict__ h2n) {
    __shared__ __bf16 ins[17136];                    // 34272 B
    int g = blockIdx.x, b = blockIdx.y;              // g in [0,19)
    int oh0 = g * 2;
    int t = threadIdx.x;
    int lane = t & 63, w = t >> 6;
    int wm = w & 1, wn = w >> 1;
    int cc = lane & 15, q = lane >> 4;

    int baseN[3], posv[3];
#pragma unroll
    for (int nt = 0; nt < 3; ++nt) {
        int p = wn * 48 + nt * 16 + cc;              // p in [0,96)
        int pv = p < 76 ? p : 75;
        int r = pv / 38, c = pv - r * 38;
        posv[nt] = p;
        baseN[nt] = (r * 42 + c) * 136 + q * 16;
    }
    floatx4 acc[2][3];
#pragma unroll
    for (int mt = 0; mt < 2; ++mt)
#pragma unroll
        for (int nt = 0; nt < 3; ++nt) acc[mt][nt] = (floatx4){0.f, 0.f, 0.f, 0.f};

    int ocA0 = wm * 32 + cc;
    for (int ic0 = 0; ic0 < 128; ic0 += 64) {
        __syncthreads();
        for (int j = t; j < 2016; j += 256) {        // 6 rows x 42 x 8 sb
            int lr = j / 336, rem = j - lr * 336;
            int ix = rem >> 3, sb = rem & 7;
            int rg = oh0 + lr;                       // <= 41, in range
            const uint4* src = (const uint4*)(h1n + ((((size_t)b * 42 + rg) * 42 + ix) * 128 + ic0 + sb * 8));
            int pos = lr * 42 + ix;
            *(uint4*)((char*)ins + (size_t)pos * 136 + sb * 16) = *src;
        }
        __syncthreads();
#pragma unroll
        for (int khw = 0; khw < 25; ++khw) {
            int kh = khw / 5, kw = khw - kh * 5;
            int doff = (kh * 42 + kw) * 136;
#pragma unroll
            for (int ks = 0; ks < 2; ++ks) {
                bf16x8 a0 = *(const bf16x8*)(w2b + (size_t)(khw * 64 + ocA0) * 128 + ic0 + ks * 32 + q * 8);
                bf16x8 a1 = *(const bf16x8*)(w2b + (size_t)(khw * 64 + ocA0 + 16) * 128 + ic0 + ks * 32 + q * 8);
#pragma unroll
                for (int nt = 0; nt < 3; ++nt) {
                    bf16x8 bfr = *(const bf16x8*)((char*)ins + baseN[nt] + doff + ks * 64);
                    acc[0][nt] = __builtin_amdgcn_mfma_f32_16x16x32_bf16(a0, bfr, acc[0][nt], 0, 0, 0);
                    acc[1][nt] = __builtin_amdgcn_mfma_f32_16x16x32_bf16(a1, bfr, acc[1][nt], 0, 0, 0);
                }
            }
        }
    }
#pragma unroll
    for (int mt = 0; mt < 2; ++mt) {
        int oc0 = wm * 32 + mt * 16 + q * 4;
        float4 bv = *(const float4*)(b2 + oc0);
#pragma unroll
        for (int nt = 0; nt < 3; ++nt) {
            int p = posv[nt];
            if (p < 76) {
                int r = p / 38, c = p - r * 38;
                int oh = oh0 + r;                    // <= 37, in range
                bf16x4 pk;
                pk.x = (__bf16)(acc[mt][nt][0] + bv.x);
                pk.y = (__bf16)(acc[mt][nt][1] + bv.y);
                pk.z = (__bf16)(acc[mt][nt][2] + bv.z);
                pk.w = (__bf16)(acc[mt][nt][3] + bv.w);
                *(bf16x4*)(h2n + ((((size_t)b * 38 + oh) * 38 + c) * 64 + oc0)) = pk;
            }
        }
    }
}

// ---- caps conv 8x8 s2 via MFMA: h2n NHWC bf16 -> hcn NHWC fp32 ------------
__global__ __launch_bounds__(256, 2) void k_convcaps(const __bf16* __restrict__ h2n,
                                                     const __bf16* __restrict__ wcb,
                                                     const float* __restrict__ bc,
                                                     float* __restrict__ hcn) {
    __shared__ __bf16 ins[13680];                    // 380 * 72 B = 27360 B
    int g = blockIdx.x, b = blockIdx.y;              // g in [0,8)
    int t = threadIdx.x;
    int lane = t & 63, w = t >> 6;
    int cc = lane & 15, q = lane >> 4;

    floatx4 acc[2][2];
#pragma unroll
    for (int mt = 0; mt < 2; ++mt)
#pragma unroll
        for (int nt = 0; nt < 2; ++nt) acc[mt][nt] = (floatx4){0.f, 0.f, 0.f, 0.f};

    int ocA = w * 32 + cc;
    int rbase = cc * 72 + q * 16;
    for (int ic0 = 0; ic0 < 64; ic0 += 32) {
        __syncthreads();
        for (int j = t; j < 1520; j += 256) {
            int r = j / 152, rem = j - r * 152;
            int c = rem >> 2, s = rem & 3;
            const uint4* src = (const uint4*)(h2n + ((((size_t)b * 38 + 4 * g + r) * 38 + c) * 64 + ic0 + s * 8));
            int X = (r * 2 + (c & 1)) * 19 + (c >> 1);
            *(uint4*)((char*)ins + X * 72 + s * 16) = *src;
        }
        __syncthreads();
#pragma unroll
        for (int khw = 0; khw < 64; ++khw) {
            int kh = khw >> 3, kw = khw & 7;
            int par = kw & 1, k2 = kw >> 1;
            bf16x8 a0 = *(const bf16x8*)(wcb + (size_t)(khw * 128 + ocA) * 64 + ic0 + q * 8);
            bf16x8 a1 = *(const bf16x8*)(wcb + (size_t)(khw * 128 + ocA + 16) * 64 + ic0 + q * 8);
#pragma unroll
            for (int nt = 0; nt < 2; ++nt) {
                int doff = (((2 * nt + kh) * 2 + par) * 19 + k2) * 72;
                bf16x8 bfr = *(const bf16x8*)((char*)ins + rbase + doff);
                acc[0][nt] = __builtin_amdgcn_mfma_f32_16x16x32_bf16(a0, bfr, acc[0][nt], 0, 0, 0);
                acc[1][nt] = __builtin_amdgcn_mfma_f32_16x16x32_bf16(a1, bfr, acc[1][nt], 0, 0, 0);
            }
        }
    }
#pragma unroll
    for (int mt = 0; mt < 2; ++mt) {
        int oc0 = w * 32 + mt * 16 + q * 4;
        float4 bv = *(const float4*)(bc + oc0);
#pragma unroll
        for (int nt = 0; nt < 2; ++nt) {
            int oh = 2 * g + nt, ow = cc;
            float4 st;
            st.x = acc[mt][nt][0] + bv.x;
            st.y = acc[mt][nt][1] + bv.y;
            st.z = acc[mt][nt][2] + bv.z;
            st.w = acc[mt][nt][3] + bv.w;
            *(float4*)(hcn + (((size_t)b * 256 + oh * 16 + ow) * 128 + oc0)) = st;
        }
    }
}

// ---- primary-capsule reorder + squash: hcn NHWC -> u:[64,1024,32] ---------
__global__ __launch_bounds__(256) void k_squash(const float* __restrict__ hcn,
                                                float* __restrict__ u) {
    int b = blockIdx.x, capg = blockIdx.y;
    int t = threadIdx.x;
    int capl = t >> 5, i = t & 31;
    int cap = capg * 8 + capl;
    int ct = cap >> 8, rem = cap & 255;
    float val = hcn[((size_t)b * 256 + rem) * 128 + ct * 32 + i];
    float s = val * val;
#pragma unroll
    for (int off = 1; off < 32; off <<= 1) s += __shfl_xor(s, off, 64);
    float scale = (s / (1.f + s)) / sqrtf(s + EPSF);
    u[((size_t)b * 1024 + cap) * 32 + i] = val * scale;
}

// ---- u_hat: u:[64,1024,32] Wr:[1024,10,16,32] -> uhT bf16 [b][t][o][p] ----
__global__ __launch_bounds__(256) void k_uhat(const float* __restrict__ u,
                                              const float* __restrict__ Wr,
                                              __bf16* __restrict__ uhT) {
    int pt = blockIdx.x;   // 16 tiles of 64 p
    int ts = blockIdx.y;   // 10
    int bz = blockIdx.z;   // 4 groups of 16 b
    int t = threadIdx.x;
    int p = pt * 64 + (t & 63);
    int q = t >> 6;
    for (int b = bz * 16 + q; b < bz * 16 + 16; b += 4) {
        float4 uu[8];
        const float4* up = (const float4*)(u + ((size_t)b * 1024 + p) * 32);
#pragma unroll
        for (int j = 0; j < 8; ++j) uu[j] = up[j];
#pragma unroll
        for (int o = 0; o < 16; ++o) {
            const float4* wp = (const float4*)(Wr + (((size_t)p * 10 + ts) * 16 + o) * 32);
            float4 a = {0.f, 0.f, 0.f, 0.f};
#pragma unroll
            for (int j = 0; j < 8; ++j) {
                float4 w4 = wp[j];
                a.x = fmaf(uu[j].x, w4.x, a.x);
                a.y = fmaf(uu[j].y, w4.y, a.y);
                a.z = fmaf(uu[j].z, w4.z, a.z);
                a.w = fmaf(uu[j].w, w4.w, a.w);
            }
            uhT[(((size_t)b * 10 + ts) * 16 + o) * 1024 + p] = (__bf16)((a.x + a.y) + (a.z + a.w));
        }
    }
}

// ---- fused dynamic routing: 3 iterations in one kernel --------------------
// grid = 64 (one block per image). b_log in registers (thread owns p =
// kk*512 + 2t + e), v in LDS, uhT slice (320 KB) re-read from L2 each pass.
__global__ __launch_bounds__(256) void k_route_all(const __bf16* __restrict__ uhT,
                                                   float* __restrict__ out) {
    __shared__ float vs[10][16];
    __shared__ float sred[4][10][16];
    int b = blockIdx.x;
    int t = threadIdx.x;
    int lane = t & 63, wid = t >> 6;
    const uint* uhb = (const uint*)(uhT + (size_t)b * 163840);

    float bl[10][2][2];
#pragma unroll
    for (int tt = 0; tt < 10; ++tt)
#pragma unroll
        for (int kk = 0; kk < 2; ++kk)
#pragma unroll
            for (int e = 0; e < 2; ++e) bl[tt][kk][e] = 0.f;

    for (int round = 0; round < 3; ++round) {
        float den[2][2] = {{0.f, 0.f}, {0.f, 0.f}};
        if (round > 0) {
#pragma unroll
            for (int tt = 0; tt < 10; ++tt)
#pragma unroll
                for (int kk = 0; kk < 2; ++kk)
#pragma unroll
                    for (int e = 0; e < 2; ++e)
                        den[kk][e] += __expf(bl[tt][kk][e]);
        }
        // s-step: s[tt][o] = sum_p c * uh
        for (int tt = 0; tt < 10; ++tt) {
            float c[2][2];
#pragma unroll
            for (int kk = 0; kk < 2; ++kk)
#pragma unroll
                for (int e = 0; e < 2; ++e)
                    c[kk][e] = (round == 0) ? 0.1f : __expf(bl[tt][kk][e]) / den[kk][e];
            float sacc[16];
#pragma unroll
            for (int o = 0; o < 16; ++o) sacc[o] = 0.f;
#pragma unroll
            for (int o = 0; o < 16; ++o) {
#pragma unroll
                for (int kk = 0; kk < 2; ++kk) {
                    uint v = uhb[(tt * 16 + o) * 512 + kk * 256 + t];
                    sacc[o] = fmaf(c[kk][0], __uint_as_float(v << 16), sacc[o]);
                    sacc[o] = fmaf(c[kk][1], __uint_as_float(v & 0xffff0000u), sacc[o]);
                }
            }
#pragma unroll
            for (int o = 0; o < 16; ++o) {
                float v = sacc[o];
#pragma unroll
                for (int off = 32; off >= 1; off >>= 1) v += __shfl_xor(v, off, 64);
                if (lane == 0) sred[wid][tt][o] = v;
            }
        }
        __syncthreads();
        // squash (threads 0..159: tt = t/16, o = t%16)
        if (t < 160) {
            int tt = t >> 4, o = t & 15;
            float s = (sred[0][tt][o] + sred[1][tt][o]) + (sred[2][tt][o] + sred[3][tt][o]);
            float n2 = s * s;
#pragma unroll
            for (int off = 1; off < 16; off <<= 1) n2 += __shfl_xor(n2, off, 16);
            float scale = (n2 / (1.f + n2)) / sqrtf(n2 + EPSF);
            vs[tt][o] = s * scale;
            if (round == 2 && o == 0)
                out[b * 10 + tt] = sqrtf(n2 * scale * scale + EPSF);
        }
        __syncthreads();
        // b-step: bl += sum_o uh * v  (skip on last round)
        if (round < 2) {
            for (int tt = 0; tt < 10; ++tt) {
                float d00 = 0.f, d01 = 0.f, d10 = 0.f, d11 = 0.f;
#pragma unroll
                for (int o = 0; o < 16; ++o) {
                    float vso = vs[tt][o];
                    uint v0 = uhb[(tt * 16 + o) * 512 + t];
                    uint v1 = uhb[(tt * 16 + o) * 512 + 256 + t];
                    d00 = fmaf(__uint_as_float(v0 << 16), vso, d00);
                    d01 = fmaf(__uint_as_float(v0 & 0xffff0000u), vso, d01);
                    d10 = fmaf(__uint_as_float(v1 << 16), vso, d10);
                    d11 = fmaf(__uint_as_float(v1 & 0xffff0000u), vso, d11);
                }
                bl[tt][0][0] += d00; bl[tt][0][1] += d01;
                bl[tt][1][0] += d10; bl[tt][1][1] += d11;
            }
        }
    }
}

// ---------------------------------------------------------------------------
extern "C" void kernel_launch(void* const* d_in, const int* in_sizes, int n_in,
                              void* d_out, int out_size, void* d_ws, size_t ws_size,
                              hipStream_t stream) {
    const float* x  = (const float*)d_in[0];
    const float* w1 = (const float*)d_in[1];
    const float* b1 = (const float*)d_in[2];
    const float* w2 = (const float*)d_in[3];
    const float* b2 = (const float*)d_in[4];
    const float* wc = (const float*)d_in[5];
    const float* bc = (const float*)d_in[6];
    const float* Wr = (const float*)d_in[7];
    float* out = (float*)d_out;
    float* ws  = (float*)d_ws;

    // workspace layout (float offsets)
    __bf16* w2b = (__bf16*)(ws);                  // 204800 bf16
    __bf16* wcb = (__bf16*)(ws + 102400);         // 524288 bf16
    __bf16* w1b = (__bf16*)(ws + 364544);         // 12288 bf16
    __bf16* h1n = (__bf16*)(ws + 375040);         // 14450688 bf16
    __bf16* h2n = (__bf16*)(ws + 7600384);        // 5914624 bf16
    float*  hcn = ws + 10557696;                  // 2097152 f
    float*  u   = ws + 12654848;                  // 2097152 f
    __bf16* uhT = (__bf16*)(ws + 375040);         // 10485760 bf16, overlays h1n (dead)

    k_t_w1b<<<48, 256, 0, stream>>>(w1, w1b);
    k_t_w2b<<<800, 256, 0, stream>>>(w2, w2b);
    k_t_wcb<<<2048, 256, 0, stream>>>(wc, wcb);
    k_conv1_mfma<<<dim3(42, 2, 64), 256, 0, stream>>>(x, w1b, b1, h1n);
    k_conv2<<<dim3(19, 64), 256, 0, stream>>>(h1n, w2b, b2, h2n);
    k_convcaps<<<dim3(8, 64), 256, 0, stream>>>(h2n, wcb, bc, hcn);
    k_squash<<<dim3(64, 128), 256, 0, stream>>>(hcn, u);
    k_uhat<<<dim3(16, 10, 4), 256, 0, stream>>>(u, Wr, uhT);
    k_route_all<<<64, 256, 0, stream>>>(uhT, out);
}

// Round 9
// 522.078 us; speedup vs baseline: 1.3838x; 1.3838x over previous
//
#include <hip/hip_runtime.h>
#include <hip/hip_bf16.h>
#include <math.h>

// ---------------------------------------------------------------------------
// GuoCapSAREncoder round 9: REVERT routing fusion (round 8's k_route_all had
// VGPR=256 + 64-block grid -> 25% of CUs, latency-serialized, 240-296 us).
// Back to round-7's 5 small routing kernels (640-block grids). KEEP round-8
// conv2 2-output-row re-grid (1216 blocks). conv1/convcaps/uhat unchanged.
// ---------------------------------------------------------------------------

#define EPSF 1e-8f

typedef __bf16 bf16x8 __attribute__((ext_vector_type(8)));
typedef __bf16 bf16x4 __attribute__((ext_vector_type(4)));
typedef float floatx4 __attribute__((ext_vector_type(4)));

// ---- weight transposes ----------------------------------------------------
__global__ __launch_bounds__(256) void k_t_w1b(const float* __restrict__ w1, __bf16* __restrict__ w1b) {
    int i = blockIdx.x * 256 + threadIdx.x;          // 12*128*8 = 12288
    if (i >= 12288) return;
    int kt = i >> 10, oc = (i >> 3) & 127, j = i & 7;
    int k = kt * 8 + j;
    w1b[i] = (__bf16)(k < 81 ? w1[oc * 81 + k] : 0.f);
}

__global__ __launch_bounds__(256) void k_t_w2b(const float* __restrict__ w2, __bf16* __restrict__ w2b) {
    int j = blockIdx.x * 256 + threadIdx.x;          // 204800
    if (j >= 204800) return;
    int khw = j / 8192, r2 = j & 8191;
    int oc = r2 >> 7, ic = r2 & 127;
    w2b[j] = (__bf16)w2[(oc * 128 + ic) * 25 + khw];
}

__global__ __launch_bounds__(256) void k_t_wcb(const float* __restrict__ wc, __bf16* __restrict__ wcb) {
    int j = blockIdx.x * 256 + threadIdx.x;          // 524288
    if (j >= 524288) return;
    int khw = j / 8192, r2 = j & 8191;
    int oc = r2 >> 6, ic = r2 & 63;
    wcb[j] = (__bf16)wc[(oc * 64 + ic) * 64 + khw];
}

// ---- conv1 9x9 + ReLU + maxpool2 via MFMA -> h1n NHWC bf16 [b][42][42][128]
__global__ __launch_bounds__(256, 3) void k_conv1_mfma(const float* __restrict__ x,
                                                       const __bf16* __restrict__ w1b,
                                                       const float* __restrict__ b1,
                                                       __bf16* __restrict__ h1n) {
    __shared__ float xs[960];                        // 10 rows x 92 fp32 (+pad)
    __shared__ __bf16 Bl[18432];                     // 12kt x 2row x 96pos x 8j
    int py = blockIdx.x, ocg = blockIdx.y, b = blockIdx.z;
    int t = threadIdx.x;
    int lane = t & 63, w = t >> 6;
    int cc = lane & 15, q = lane >> 4;

    const float* xb = x + (size_t)b * 8464 + 2 * py * 92;
    for (int j = t; j < 920; j += 256) xs[j] = xb[j];

    int ocA = ocg * 64 + w * 16 + cc;
    bf16x8 af[3];
#pragma unroll
    for (int ks = 0; ks < 3; ++ks)
        af[ks] = *(const bf16x8*)(w1b + ((ks * 4 + q) * 128 + ocA) * 8);

    __syncthreads();

    if (t < 192) {
        int row = t / 96, pos = t - (t / 96) * 96;
        int sbase = row * 92 + pos;
        bool pvalid = pos < 84;
#pragma unroll
        for (int kt = 0; kt < 12; ++kt) {
            bf16x8 pk;
#pragma unroll
            for (int j = 0; j < 8; ++j) {
                int k = kt * 8 + j;
                int kh = k / 9, kw = k - kh * 9;
                float v = (pvalid && k < 81) ? xs[sbase + kh * 92 + kw] : 0.f;
                pk[j] = (__bf16)v;
            }
            *(bf16x8*)(Bl + ((kt * 2 + row) * 96 + pos) * 8) = pk;
        }
    }
    __syncthreads();

    floatx4 acc[2][6];
    const char* Bb = (const char*)Bl + cc * 16 + q * 3072;
#pragma unroll
    for (int rr = 0; rr < 2; ++rr)
#pragma unroll
        for (int n6 = 0; n6 < 6; ++n6) {
            floatx4 a = (floatx4){0.f, 0.f, 0.f, 0.f};
#pragma unroll
            for (int ks = 0; ks < 3; ++ks) {
                bf16x8 bf = *(const bf16x8*)(Bb + ks * 12288 + rr * 1536 + n6 * 256);
                a = __builtin_amdgcn_mfma_f32_16x16x32_bf16(af[ks], bf, a, 0, 0, 0);
            }
            acc[rr][n6] = a;
        }

    int oc0 = ocg * 64 + w * 16 + q * 4;
    float4 bv = *(const float4*)(b1 + oc0);
    size_t obase = (((size_t)b * 42 + py) * 42) * 128 + oc0;
#pragma unroll
    for (int n6 = 0; n6 < 6; ++n6) {
        bf16x4 pk;
#pragma unroll
        for (int r = 0; r < 4; ++r) {
            float vert = fmaxf(acc[0][n6][r], acc[1][n6][r]);
            float hz = fmaxf(vert, __shfl_xor(vert, 1, 64));
            float pooled = fmaxf(hz + ((const float*)&bv)[r], 0.f);
            pk[r] = (__bf16)pooled;
        }
        if ((cc & 1) == 0) {
            int px = n6 * 8 + (cc >> 1);
            if (px < 42)
                *(bf16x4*)(h1n + obase + (size_t)px * 128) = pk;
        }
    }
}

// ---- conv2 5x5 via MFMA: h1n NHWC bf16 -> h2n NHWC bf16 [b][38][38][64] ---
// 2-output-row blocks: grid (19,64)=1216. LDS 252 pos * 136 B = 34272 B.
__global__ __launch_bounds__(256, 2) void k_conv2(const __bf16* __restrict__ h1n,
                                                  const __bf16* __restrict__ w2b,
                                                  const float* __restrict__ b2,
                                                  __bf16* __restrict__ h2n) {
    __shared__ __bf16 ins[17136];                    // 34272 B
    int g = blockIdx.x, b = blockIdx.y;              // g in [0,19)
    int oh0 = g * 2;
    int t = threadIdx.x;
    int lane = t & 63, w = t >> 6;
    int wm = w & 1, wn = w >> 1;
    int cc = lane & 15, q = lane >> 4;

    int baseN[3], posv[3];
#pragma unroll
    for (int nt = 0; nt < 3; ++nt) {
        int p = wn * 48 + nt * 16 + cc;              // p in [0,96)
        int pv = p < 76 ? p : 75;
        int r = pv / 38, c = pv - r * 38;
        posv[nt] = p;
        baseN[nt] = (r * 42 + c) * 136 + q * 16;
    }
    floatx4 acc[2][3];
#pragma unroll
    for (int mt = 0; mt < 2; ++mt)
#pragma unroll
        for (int nt = 0; nt < 3; ++nt) acc[mt][nt] = (floatx4){0.f, 0.f, 0.f, 0.f};

    int ocA0 = wm * 32 + cc;
    for (int ic0 = 0; ic0 < 128; ic0 += 64) {
        __syncthreads();
        for (int j = t; j < 2016; j += 256) {        // 6 rows x 42 x 8 sb
            int lr = j / 336, rem = j - lr * 336;
            int ix = rem >> 3, sb = rem & 7;
            int rg = oh0 + lr;
            const uint4* src = (const uint4*)(h1n + ((((size_t)b * 42 + rg) * 42 + ix) * 128 + ic0 + sb * 8));
            int pos = lr * 42 + ix;
            *(uint4*)((char*)ins + (size_t)pos * 136 + sb * 16) = *src;
        }
        __syncthreads();
#pragma unroll
        for (int khw = 0; khw < 25; ++khw) {
            int kh = khw / 5, kw = khw - kh * 5;
            int doff = (kh * 42 + kw) * 136;
#pragma unroll
            for (int ks = 0; ks < 2; ++ks) {
                bf16x8 a0 = *(const bf16x8*)(w2b + (size_t)(khw * 64 + ocA0) * 128 + ic0 + ks * 32 + q * 8);
                bf16x8 a1 = *(const bf16x8*)(w2b + (size_t)(khw * 64 + ocA0 + 16) * 128 + ic0 + ks * 32 + q * 8);
#pragma unroll
                for (int nt = 0; nt < 3; ++nt) {
                    bf16x8 bfr = *(const bf16x8*)((char*)ins + baseN[nt] + doff + ks * 64);
                    acc[0][nt] = __builtin_amdgcn_mfma_f32_16x16x32_bf16(a0, bfr, acc[0][nt], 0, 0, 0);
                    acc[1][nt] = __builtin_amdgcn_mfma_f32_16x16x32_bf16(a1, bfr, acc[1][nt], 0, 0, 0);
                }
            }
        }
    }
#pragma unroll
    for (int mt = 0; mt < 2; ++mt) {
        int oc0 = wm * 32 + mt * 16 + q * 4;
        float4 bv = *(const float4*)(b2 + oc0);
#pragma unroll
        for (int nt = 0; nt < 3; ++nt) {
            int p = posv[nt];
            if (p < 76) {
                int r = p / 38, c = p - r * 38;
                int oh = oh0 + r;
                bf16x4 pk;
                pk.x = (__bf16)(acc[mt][nt][0] + bv.x);
                pk.y = (__bf16)(acc[mt][nt][1] + bv.y);
                pk.z = (__bf16)(acc[mt][nt][2] + bv.z);
                pk.w = (__bf16)(acc[mt][nt][3] + bv.w);
                *(bf16x4*)(h2n + ((((size_t)b * 38 + oh) * 38 + c) * 64 + oc0)) = pk;
            }
        }
    }
}

// ---- caps conv 8x8 s2 via MFMA: h2n NHWC bf16 -> hcn NHWC fp32 ------------
__global__ __launch_bounds__(256, 2) void k_convcaps(const __bf16* __restrict__ h2n,
                                                     const __bf16* __restrict__ wcb,
                                                     const float* __restrict__ bc,
                                                     float* __restrict__ hcn) {
    __shared__ __bf16 ins[13680];                    // 380 * 72 B = 27360 B
    int g = blockIdx.x, b = blockIdx.y;              // g in [0,8)
    int t = threadIdx.x;
    int lane = t & 63, w = t >> 6;
    int cc = lane & 15, q = lane >> 4;

    floatx4 acc[2][2];
#pragma unroll
    for (int mt = 0; mt < 2; ++mt)
#pragma unroll
        for (int nt = 0; nt < 2; ++nt) acc[mt][nt] = (floatx4){0.f, 0.f, 0.f, 0.f};

    int ocA = w * 32 + cc;
    int rbase = cc * 72 + q * 16;
    for (int ic0 = 0; ic0 < 64; ic0 += 32) {
        __syncthreads();
        for (int j = t; j < 1520; j += 256) {
            int r = j / 152, rem = j - r * 152;
            int c = rem >> 2, s = rem & 3;
            const uint4* src = (const uint4*)(h2n + ((((size_t)b * 38 + 4 * g + r) * 38 + c) * 64 + ic0 + s * 8));
            int X = (r * 2 + (c & 1)) * 19 + (c >> 1);
            *(uint4*)((char*)ins + X * 72 + s * 16) = *src;
        }
        __syncthreads();
#pragma unroll
        for (int khw = 0; khw < 64; ++khw) {
            int kh = khw >> 3, kw = khw & 7;
            int par = kw & 1, k2 = kw >> 1;
            bf16x8 a0 = *(const bf16x8*)(wcb + (size_t)(khw * 128 + ocA) * 64 + ic0 + q * 8);
            bf16x8 a1 = *(const bf16x8*)(wcb + (size_t)(khw * 128 + ocA + 16) * 64 + ic0 + q * 8);
#pragma unroll
            for (int nt = 0; nt < 2; ++nt) {
                int doff = (((2 * nt + kh) * 2 + par) * 19 + k2) * 72;
                bf16x8 bfr = *(const bf16x8*)((char*)ins + rbase + doff);
                acc[0][nt] = __builtin_amdgcn_mfma_f32_16x16x32_bf16(a0, bfr, acc[0][nt], 0, 0, 0);
                acc[1][nt] = __builtin_amdgcn_mfma_f32_16x16x32_bf16(a1, bfr, acc[1][nt], 0, 0, 0);
            }
        }
    }
#pragma unroll
    for (int mt = 0; mt < 2; ++mt) {
        int oc0 = w * 32 + mt * 16 + q * 4;
        float4 bv = *(const float4*)(bc + oc0);
#pragma unroll
        for (int nt = 0; nt < 2; ++nt) {
            int oh = 2 * g + nt, ow = cc;
            float4 st;
            st.x = acc[mt][nt][0] + bv.x;
            st.y = acc[mt][nt][1] + bv.y;
            st.z = acc[mt][nt][2] + bv.z;
            st.w = acc[mt][nt][3] + bv.w;
            *(float4*)(hcn + (((size_t)b * 256 + oh * 16 + ow) * 128 + oc0)) = st;
        }
    }
}

// ---- primary-capsule reorder + squash: hcn NHWC -> u:[64,1024,32] ---------
__global__ __launch_bounds__(256) void k_squash(const float* __restrict__ hcn,
                                                float* __restrict__ u) {
    int b = blockIdx.x, capg = blockIdx.y;
    int t = threadIdx.x;
    int capl = t >> 5, i = t & 31;
    int cap = capg * 8 + capl;
    int ct = cap >> 8, rem = cap & 255;
    float val = hcn[((size_t)b * 256 + rem) * 128 + ct * 32 + i];
    float s = val * val;
#pragma unroll
    for (int off = 1; off < 32; off <<= 1) s += __shfl_xor(s, off, 64);
    float scale = (s / (1.f + s)) / sqrtf(s + EPSF);
    u[((size_t)b * 1024 + cap) * 32 + i] = val * scale;
}

// ---- u_hat: u:[64,1024,32] Wr:[1024,10,16,32] -> uhT bf16 [b][t][o][p] ----
__global__ __launch_bounds__(256) void k_uhat(const float* __restrict__ u,
                                              const float* __restrict__ Wr,
                                              __bf16* __restrict__ uhT) {
    int pt = blockIdx.x;   // 16 tiles of 64 p
    int ts = blockIdx.y;   // 10
    int bz = blockIdx.z;   // 4 groups of 16 b
    int t = threadIdx.x;
    int p = pt * 64 + (t & 63);
    int q = t >> 6;
    for (int b = bz * 16 + q; b < bz * 16 + 16; b += 4) {
        float4 uu[8];
        const float4* up = (const float4*)(u + ((size_t)b * 1024 + p) * 32);
#pragma unroll
        for (int j = 0; j < 8; ++j) uu[j] = up[j];
#pragma unroll
        for (int o = 0; o < 16; ++o) {
            const float4* wp = (const float4*)(Wr + (((size_t)p * 10 + ts) * 16 + o) * 32);
            float4 a = {0.f, 0.f, 0.f, 0.f};
#pragma unroll
            for (int j = 0; j < 8; ++j) {
                float4 w4 = wp[j];
                a.x = fmaf(uu[j].x, w4.x, a.x);
                a.y = fmaf(uu[j].y, w4.y, a.y);
                a.z = fmaf(uu[j].z, w4.z, a.z);
                a.w = fmaf(uu[j].w, w4.w, a.w);
            }
            uhT[(((size_t)b * 10 + ts) * 16 + o) * 1024 + p] = (__bf16)((a.x + a.y) + (a.z + a.w));
        }
    }
}

// ---- routing: s = sum_p softmax(bl)_pt * u_hat ; v = squash(s) ------------
__global__ __launch_bounds__(256) void k_route_s(const __bf16* __restrict__ uhT,
                                                 const float* __restrict__ bl,
                                                 float* __restrict__ vout,
                                                 float* __restrict__ out,
                                                 int first, int last) {
    __shared__ float sred[4][16];
    int b = blockIdx.x, tt = blockIdx.y;
    int t = threadIdx.x;
    float acc[16];
#pragma unroll
    for (int o = 0; o < 16; ++o) acc[o] = 0.f;
    const float* blb = bl + b * 10240;
    const __bf16* uhb = uhT + ((size_t)b * 10 + tt) * 16384;
    for (int p = t; p < 1024; p += 256) {
        float c;
        if (first) {
            c = 0.1f;
        } else {
            float den = 0.f, et = 0.f;
#pragma unroll
            for (int tp = 0; tp < 10; ++tp) {
                float e = expf(blb[tp * 1024 + p]);
                den += e;
                if (tp == tt) et = e;
            }
            c = et / den;
        }
#pragma unroll
        for (int o = 0; o < 16; ++o)
            acc[o] = fmaf(c, (float)uhb[o * 1024 + p], acc[o]);
    }
    int lane = t & 63, wid = t >> 6;
#pragma unroll
    for (int o = 0; o < 16; ++o) {
        float v = acc[o];
#pragma unroll
        for (int off = 32; off >= 1; off >>= 1) v += __shfl_xor(v, off, 64);
        if (lane == 0) sred[wid][o] = v;
    }
    __syncthreads();
    if (t < 16) {
        float s = (sred[0][t] + sred[1][t]) + (sred[2][t] + sred[3][t]);
        float n2 = s * s;
#pragma unroll
        for (int off = 1; off < 16; off <<= 1) n2 += __shfl_xor(n2, off, 16);
        float scale = (n2 / (1.f + n2)) / sqrtf(n2 + EPSF);
        vout[(b * 10 + tt) * 16 + t] = s * scale;
        if (last && t == 0) {
            float sv2 = n2 * scale * scale;
            out[b * 10 + tt] = sqrtf(sv2 + EPSF);
        }
    }
}

// ---- routing: bl (+)= sum_o u_hat * v -------------------------------------
__global__ __launch_bounds__(256) void k_route_b(const __bf16* __restrict__ uhT,
                                                 const float* __restrict__ vv,
                                                 float* __restrict__ bl,
                                                 int first) {
    __shared__ float vs[16];
    int b = blockIdx.x, tt = blockIdx.y;
    int t = threadIdx.x;
    if (t < 16) vs[t] = vv[(b * 10 + tt) * 16 + t];
    __syncthreads();
    const __bf16* uhb = uhT + ((size_t)b * 10 + tt) * 16384;
    float* blb = bl + (b * 10 + tt) * 1024;
    for (int p = t; p < 1024; p += 256) {
        float d = 0.f;
#pragma unroll
        for (int o = 0; o < 16; ++o) d = fmaf((float)uhb[o * 1024 + p], vs[o], d);
        blb[p] = first ? d : (blb[p] + d);
    }
}

// ---------------------------------------------------------------------------
extern "C" void kernel_launch(void* const* d_in, const int* in_sizes, int n_in,
                              void* d_out, int out_size, void* d_ws, size_t ws_size,
                              hipStream_t stream) {
    const float* x  = (const float*)d_in[0];
    const float* w1 = (const float*)d_in[1];
    const float* b1 = (const float*)d_in[2];
    const float* w2 = (const float*)d_in[3];
    const float* b2 = (const float*)d_in[4];
    const float* wc = (const float*)d_in[5];
    const float* bc = (const float*)d_in[6];
    const float* Wr = (const float*)d_in[7];
    float* out = (float*)d_out;
    float* ws  = (float*)d_ws;

    // workspace layout (float offsets)
    __bf16* w2b = (__bf16*)(ws);                  // 204800 bf16
    __bf16* wcb = (__bf16*)(ws + 102400);         // 524288 bf16
    __bf16* w1b = (__bf16*)(ws + 364544);         // 12288 bf16
    __bf16* h1n = (__bf16*)(ws + 375040);         // 14450688 bf16
    __bf16* h2n = (__bf16*)(ws + 7600384);        // 5914624 bf16
    float*  hcn = ws + 10557696;                  // 2097152 f
    float*  u   = ws + 12654848;                  // 2097152 f
    float*  bl  = ws + 14752000;                  // 655360 f
    float*  vv  = ws + 15407360;                  // 10240 f
    __bf16* uhT = (__bf16*)(ws + 375040);         // overlays h1n (dead by k_uhat)

    k_t_w1b<<<48, 256, 0, stream>>>(w1, w1b);
    k_t_w2b<<<800, 256, 0, stream>>>(w2, w2b);
    k_t_wcb<<<2048, 256, 0, stream>>>(wc, wcb);
    k_conv1_mfma<<<dim3(42, 2, 64), 256, 0, stream>>>(x, w1b, b1, h1n);
    k_conv2<<<dim3(19, 64), 256, 0, stream>>>(h1n, w2b, b2, h2n);
    k_convcaps<<<dim3(8, 64), 256, 0, stream>>>(h2n, wcb, bc, hcn);
    k_squash<<<dim3(64, 128), 256, 0, stream>>>(hcn, u);
    k_uhat<<<dim3(16, 10, 4), 256, 0, stream>>>(u, Wr, uhT);
    k_route_s<<<dim3(64, 10), 256, 0, stream>>>(uhT, bl, vv, out, 1, 0);
    k_route_b<<<dim3(64, 10), 256, 0, stream>>>(uhT, vv, bl, 1);
    k_route_s<<<dim3(64, 10), 256, 0, stream>>>(uhT, bl, vv, out, 0, 0);
    k_route_b<<<dim3(64, 10), 256, 0, stream>>>(uhT, vv, bl, 0);
    k_route_s<<<dim3(64, 10), 256, 0, stream>>>(uhT, bl, vv, out, 0, 1);
}

// Round 10
// 455.504 us; speedup vs baseline: 1.5860x; 1.1462x over previous
//
#include <hip/hip_runtime.h>
#include <hip/hip_bf16.h>
#include <math.h>

// ---------------------------------------------------------------------------
// GuoCapSAREncoder round 10:
//  - conv2 rewritten with mfma_f32_32x32x16_bf16: wave = 2mt x 2nt (B-frag
//    reused across both 32-oc tiles -> 2x MACs/LDS-byte vs 16x16), 192-thread
//    blocks, 5 output rows, grid (8,64)=512 = 2 blocks/CU exactly.
//    32x32 C/D layout: col=lane&31, row=(reg&3)+8*(reg>>2)+4*(lane>>5).
//  - k_uhat re-gridded (16,10,2): Wr read <=2x total (was 16x -> L3-bound).
//  - conv1/convcaps/squash/routing unchanged from round 9.
// ---------------------------------------------------------------------------

#define EPSF 1e-8f

typedef __bf16 bf16x8 __attribute__((ext_vector_type(8)));
typedef __bf16 bf16x4 __attribute__((ext_vector_type(4)));
typedef float floatx4 __attribute__((ext_vector_type(4)));
typedef float floatx16 __attribute__((ext_vector_type(16)));

// ---- weight transposes ----------------------------------------------------
__global__ __launch_bounds__(256) void k_t_w1b(const float* __restrict__ w1, __bf16* __restrict__ w1b) {
    int i = blockIdx.x * 256 + threadIdx.x;          // 12*128*8 = 12288
    if (i >= 12288) return;
    int kt = i >> 10, oc = (i >> 3) & 127, j = i & 7;
    int k = kt * 8 + j;
    w1b[i] = (__bf16)(k < 81 ? w1[oc * 81 + k] : 0.f);
}

__global__ __launch_bounds__(256) void k_t_w2b(const float* __restrict__ w2, __bf16* __restrict__ w2b) {
    int j = blockIdx.x * 256 + threadIdx.x;          // 204800
    if (j >= 204800) return;
    int khw = j / 8192, r2 = j & 8191;
    int oc = r2 >> 7, ic = r2 & 127;
    w2b[j] = (__bf16)w2[(oc * 128 + ic) * 25 + khw];
}

__global__ __launch_bounds__(256) void k_t_wcb(const float* __restrict__ wc, __bf16* __restrict__ wcb) {
    int j = blockIdx.x * 256 + threadIdx.x;          // 524288
    if (j >= 524288) return;
    int khw = j / 8192, r2 = j & 8191;
    int oc = r2 >> 6, ic = r2 & 63;
    wcb[j] = (__bf16)wc[(oc * 64 + ic) * 64 + khw];
}

// ---- conv1 9x9 + ReLU + maxpool2 via MFMA -> h1n NHWC bf16 [b][42][42][128]
__global__ __launch_bounds__(256, 3) void k_conv1_mfma(const float* __restrict__ x,
                                                       const __bf16* __restrict__ w1b,
                                                       const float* __restrict__ b1,
                                                       __bf16* __restrict__ h1n) {
    __shared__ float xs[960];                        // 10 rows x 92 fp32 (+pad)
    __shared__ __bf16 Bl[18432];                     // 12kt x 2row x 96pos x 8j
    int py = blockIdx.x, ocg = blockIdx.y, b = blockIdx.z;
    int t = threadIdx.x;
    int lane = t & 63, w = t >> 6;
    int cc = lane & 15, q = lane >> 4;

    const float* xb = x + (size_t)b * 8464 + 2 * py * 92;
    for (int j = t; j < 920; j += 256) xs[j] = xb[j];

    int ocA = ocg * 64 + w * 16 + cc;
    bf16x8 af[3];
#pragma unroll
    for (int ks = 0; ks < 3; ++ks)
        af[ks] = *(const bf16x8*)(w1b + ((ks * 4 + q) * 128 + ocA) * 8);

    __syncthreads();

    if (t < 192) {
        int row = t / 96, pos = t - (t / 96) * 96;
        int sbase = row * 92 + pos;
        bool pvalid = pos < 84;
#pragma unroll
        for (int kt = 0; kt < 12; ++kt) {
            bf16x8 pk;
#pragma unroll
            for (int j = 0; j < 8; ++j) {
                int k = kt * 8 + j;
                int kh = k / 9, kw = k - kh * 9;
                float v = (pvalid && k < 81) ? xs[sbase + kh * 92 + kw] : 0.f;
                pk[j] = (__bf16)v;
            }
            *(bf16x8*)(Bl + ((kt * 2 + row) * 96 + pos) * 8) = pk;
        }
    }
    __syncthreads();

    floatx4 acc[2][6];
    const char* Bb = (const char*)Bl + cc * 16 + q * 3072;
#pragma unroll
    for (int rr = 0; rr < 2; ++rr)
#pragma unroll
        for (int n6 = 0; n6 < 6; ++n6) {
            floatx4 a = (floatx4){0.f, 0.f, 0.f, 0.f};
#pragma unroll
            for (int ks = 0; ks < 3; ++ks) {
                bf16x8 bf = *(const bf16x8*)(Bb + ks * 12288 + rr * 1536 + n6 * 256);
                a = __builtin_amdgcn_mfma_f32_16x16x32_bf16(af[ks], bf, a, 0, 0, 0);
            }
            acc[rr][n6] = a;
        }

    int oc0 = ocg * 64 + w * 16 + q * 4;
    float4 bv = *(const float4*)(b1 + oc0);
    size_t obase = (((size_t)b * 42 + py) * 42) * 128 + oc0;
#pragma unroll
    for (int n6 = 0; n6 < 6; ++n6) {
        bf16x4 pk;
#pragma unroll
        for (int r = 0; r < 4; ++r) {
            float vert = fmaxf(acc[0][n6][r], acc[1][n6][r]);
            float hz = fmaxf(vert, __shfl_xor(vert, 1, 64));
            float pooled = fmaxf(hz + ((const float*)&bv)[r], 0.f);
            pk[r] = (__bf16)pooled;
        }
        if ((cc & 1) == 0) {
            int px = n6 * 8 + (cc >> 1);
            if (px < 42)
                *(bf16x4*)(h1n + obase + (size_t)px * 128) = pk;
        }
    }
}

// ---- conv2 5x5 via MFMA 32x32x16: h1n NHWC -> h2n NHWC bf16 [b][38][38][64]
// Block: 192 thr (3 waves), 5 output rows (190 pos -> 6 tiles of 32).
// Wave w: tiles {2w, 2w+1} x both 32-oc M-tiles -> B-frag reused 2x.
// LDS slab: 9 input rows, pos*136 + sb*16 (pitch 34 dw = 2 mod 32 banks).
__global__ __launch_bounds__(192, 2) void k_conv2(const __bf16* __restrict__ h1n,
                                                  const __bf16* __restrict__ w2b,
                                                  const float* __restrict__ b2,
                                                  __bf16* __restrict__ h2n) {
    __shared__ __bf16 ins[25704];                    // 378 pos * 136 B = 51408 B
    int g = blockIdx.x, b = blockIdx.y;              // g in [0,8)
    int row0 = g * 5;
    int t = threadIdx.x;
    int lane = t & 63, w = t >> 6;                   // w in [0,3)
    int c32 = lane & 31, h = lane >> 5;
    int validp = (g < 7) ? 190 : 114;

    int baseN[2], posi[2];
#pragma unroll
    for (int nt = 0; nt < 2; ++nt) {
        int pi = (w * 2 + nt) * 32 + c32;
        int pc = pi < validp ? pi : validp - 1;
        int r = pc / 38, c = pc - r * 38;
        posi[nt] = pi;
        baseN[nt] = (r * 42 + c) * 136 + h * 16;
    }
    floatx16 acc[2][2];
#pragma unroll
    for (int mt = 0; mt < 2; ++mt)
#pragma unroll
        for (int nt = 0; nt < 2; ++nt)
#pragma unroll
            for (int i = 0; i < 16; ++i) acc[mt][nt][i] = 0.f;

    for (int ic0 = 0; ic0 < 128; ic0 += 64) {
        __syncthreads();
        for (int j = t; j < 3024; j += 192) {        // 9 rows x 42 x 8 sb
            int lr = j / 336, rem = j - lr * 336;
            int ix = rem >> 3, sb = rem & 7;
            int rg = row0 + lr; if (rg > 41) rg = 41;
            const uint4* src = (const uint4*)(h1n + ((((size_t)b * 42 + rg) * 42 + ix) * 128 + ic0 + sb * 8));
            int pos = lr * 42 + ix;
            *(uint4*)((char*)ins + (size_t)pos * 136 + sb * 16) = *src;
        }
        __syncthreads();
#pragma unroll
        for (int khw = 0; khw < 25; ++khw) {
            int kh = khw / 5, kw = khw - kh * 5;
            int doff = (kh * 42 + kw) * 136;
#pragma unroll
            for (int ks = 0; ks < 4; ++ks) {
                // A: k = h*8+j at ic0 + ks*16; row(oc) = c32 (+mt*32)
                bf16x8 a0 = *(const bf16x8*)(w2b + (size_t)(khw * 64 + c32) * 128 + ic0 + ks * 16 + h * 8);
                bf16x8 a1 = *(const bf16x8*)(w2b + (size_t)(khw * 64 + 32 + c32) * 128 + ic0 + ks * 16 + h * 8);
#pragma unroll
                for (int nt = 0; nt < 2; ++nt) {
                    bf16x8 bfr = *(const bf16x8*)((char*)ins + baseN[nt] + doff + ks * 32);
                    acc[0][nt] = __builtin_amdgcn_mfma_f32_32x32x16_bf16(a0, bfr, acc[0][nt], 0, 0, 0);
                    acc[1][nt] = __builtin_amdgcn_mfma_f32_32x32x16_bf16(a1, bfr, acc[1][nt], 0, 0, 0);
                }
            }
        }
    }
    // epilogue: D row = (reg&3) + 8*(reg>>2) + 4*h ; col(pos) = c32
#pragma unroll
    for (int nt = 0; nt < 2; ++nt) {
        int pi = posi[nt];
        if (pi < validp) {
            int r = pi / 38, c = pi - r * 38;
            int oh = row0 + r;
            size_t obase = (((size_t)b * 38 + oh) * 38 + c) * 64;
#pragma unroll
            for (int mt = 0; mt < 2; ++mt) {
#pragma unroll
                for (int g2 = 0; g2 < 4; ++g2) {
                    int oc0 = mt * 32 + g2 * 8 + h * 4;
                    float4 bv = *(const float4*)(b2 + oc0);
                    bf16x4 pk;
                    pk.x = (__bf16)(acc[mt][nt][g2 * 4 + 0] + bv.x);
                    pk.y = (__bf16)(acc[mt][nt][g2 * 4 + 1] + bv.y);
                    pk.z = (__bf16)(acc[mt][nt][g2 * 4 + 2] + bv.z);
                    pk.w = (__bf16)(acc[mt][nt][g2 * 4 + 3] + bv.w);
                    *(bf16x4*)(h2n + obase + oc0) = pk;
                }
            }
        }
    }
}

// ---- caps conv 8x8 s2 via MFMA: h2n NHWC bf16 -> hcn NHWC fp32 ------------
__global__ __launch_bounds__(256, 2) void k_convcaps(const __bf16* __restrict__ h2n,
                                                     const __bf16* __restrict__ wcb,
                                                     const float* __restrict__ bc,
                                                     float* __restrict__ hcn) {
    __shared__ __bf16 ins[13680];                    // 380 * 72 B = 27360 B
    int g = blockIdx.x, b = blockIdx.y;              // g in [0,8)
    int t = threadIdx.x;
    int lane = t & 63, w = t >> 6;
    int cc = lane & 15, q = lane >> 4;

    floatx4 acc[2][2];
#pragma unroll
    for (int mt = 0; mt < 2; ++mt)
#pragma unroll
        for (int nt = 0; nt < 2; ++nt) acc[mt][nt] = (floatx4){0.f, 0.f, 0.f, 0.f};

    int ocA = w * 32 + cc;
    int rbase = cc * 72 + q * 16;
    for (int ic0 = 0; ic0 < 64; ic0 += 32) {
        __syncthreads();
        for (int j = t; j < 1520; j += 256) {
            int r = j / 152, rem = j - r * 152;
            int c = rem >> 2, s = rem & 3;
            const uint4* src = (const uint4*)(h2n + ((((size_t)b * 38 + 4 * g + r) * 38 + c) * 64 + ic0 + s * 8));
            int X = (r * 2 + (c & 1)) * 19 + (c >> 1);
            *(uint4*)((char*)ins + X * 72 + s * 16) = *src;
        }
        __syncthreads();
#pragma unroll
        for (int khw = 0; khw < 64; ++khw) {
            int kh = khw >> 3, kw = khw & 7;
            int par = kw & 1, k2 = kw >> 1;
            bf16x8 a0 = *(const bf16x8*)(wcb + (size_t)(khw * 128 + ocA) * 64 + ic0 + q * 8);
            bf16x8 a1 = *(const bf16x8*)(wcb + (size_t)(khw * 128 + ocA + 16) * 64 + ic0 + q * 8);
#pragma unroll
            for (int nt = 0; nt < 2; ++nt) {
                int doff = (((2 * nt + kh) * 2 + par) * 19 + k2) * 72;
                bf16x8 bfr = *(const bf16x8*)((char*)ins + rbase + doff);
                acc[0][nt] = __builtin_amdgcn_mfma_f32_16x16x32_bf16(a0, bfr, acc[0][nt], 0, 0, 0);
                acc[1][nt] = __builtin_amdgcn_mfma_f32_16x16x32_bf16(a1, bfr, acc[1][nt], 0, 0, 0);
            }
        }
    }
#pragma unroll
    for (int mt = 0; mt < 2; ++mt) {
        int oc0 = w * 32 + mt * 16 + q * 4;
        float4 bv = *(const float4*)(bc + oc0);
#pragma unroll
        for (int nt = 0; nt < 2; ++nt) {
            int oh = 2 * g + nt, ow = cc;
            float4 st;
            st.x = acc[mt][nt][0] + bv.x;
            st.y = acc[mt][nt][1] + bv.y;
            st.z = acc[mt][nt][2] + bv.z;
            st.w = acc[mt][nt][3] + bv.w;
            *(float4*)(hcn + (((size_t)b * 256 + oh * 16 + ow) * 128 + oc0)) = st;
        }
    }
}

// ---- primary-capsule reorder + squash: hcn NHWC -> u:[64,1024,32] ---------
__global__ __launch_bounds__(256) void k_squash(const float* __restrict__ hcn,
                                                float* __restrict__ u) {
    int b = blockIdx.x, capg = blockIdx.y;
    int t = threadIdx.x;
    int capl = t >> 5, i = t & 31;
    int cap = capg * 8 + capl;
    int ct = cap >> 8, rem = cap & 255;
    float val = hcn[((size_t)b * 256 + rem) * 128 + ct * 32 + i];
    float s = val * val;
#pragma unroll
    for (int off = 1; off < 32; off <<= 1) s += __shfl_xor(s, off, 64);
    float scale = (s / (1.f + s)) / sqrtf(s + EPSF);
    u[((size_t)b * 1024 + cap) * 32 + i] = val * scale;
}

// ---- u_hat: u:[64,1024,32] Wr:[1024,10,16,32] -> uhT bf16 [b][t][o][p] ----
// grid (16 pt, 10 ts, 2 bz): each block covers 32 b -> Wr read <=2x total
// (was 16x across bz*inner -> L3-bound).
__global__ __launch_bounds__(256) void k_uhat(const float* __restrict__ u,
                                              const float* __restrict__ Wr,
                                              __bf16* __restrict__ uhT) {
    int pt = blockIdx.x;   // 16 tiles of 64 p
    int ts = blockIdx.y;   // 10
    int bz = blockIdx.z;   // 2 groups of 32 b
    int t = threadIdx.x;
    int p = pt * 64 + (t & 63);
    int q = t >> 6;
    for (int bi = 0; bi < 8; ++bi) {
        int b = bz * 32 + q * 8 + bi;
        float4 uu[8];
        const float4* up = (const float4*)(u + ((size_t)b * 1024 + p) * 32);
#pragma unroll
        for (int j = 0; j < 8; ++j) uu[j] = up[j];
#pragma unroll
        for (int o = 0; o < 16; ++o) {
            const float4* wp = (const float4*)(Wr + (((size_t)p * 10 + ts) * 16 + o) * 32);
            float4 a = {0.f, 0.f, 0.f, 0.f};
#pragma unroll
            for (int j = 0; j < 8; ++j) {
                float4 w4 = wp[j];
                a.x = fmaf(uu[j].x, w4.x, a.x);
                a.y = fmaf(uu[j].y, w4.y, a.y);
                a.z = fmaf(uu[j].z, w4.z, a.z);
                a.w = fmaf(uu[j].w, w4.w, a.w);
            }
            uhT[(((size_t)b * 10 + ts) * 16 + o) * 1024 + p] = (__bf16)((a.x + a.y) + (a.z + a.w));
        }
    }
}

// ---- routing: s = sum_p softmax(bl)_pt * u_hat ; v = squash(s) ------------
__global__ __launch_bounds__(256) void k_route_s(const __bf16* __restrict__ uhT,
                                                 const float* __restrict__ bl,
                                                 float* __restrict__ vout,
                                                 float* __restrict__ out,
                                                 int first, int last) {
    __shared__ float sred[4][16];
    int b = blockIdx.x, tt = blockIdx.y;
    int t = threadIdx.x;
    float acc[16];
#pragma unroll
    for (int o = 0; o < 16; ++o) acc[o] = 0.f;
    const float* blb = bl + b * 10240;
    const __bf16* uhb = uhT + ((size_t)b * 10 + tt) * 16384;
    for (int p = t; p < 1024; p += 256) {
        float c;
        if (first) {
            c = 0.1f;
        } else {
            float den = 0.f, et = 0.f;
#pragma unroll
            for (int tp = 0; tp < 10; ++tp) {
                float e = expf(blb[tp * 1024 + p]);
                den += e;
                if (tp == tt) et = e;
            }
            c = et / den;
        }
#pragma unroll
        for (int o = 0; o < 16; ++o)
            acc[o] = fmaf(c, (float)uhb[o * 1024 + p], acc[o]);
    }
    int lane = t & 63, wid = t >> 6;
#pragma unroll
    for (int o = 0; o < 16; ++o) {
        float v = acc[o];
#pragma unroll
        for (int off = 32; off >= 1; off >>= 1) v += __shfl_xor(v, off, 64);
        if (lane == 0) sred[wid][o] = v;
    }
    __syncthreads();
    if (t < 16) {
        float s = (sred[0][t] + sred[1][t]) + (sred[2][t] + sred[3][t]);
        float n2 = s * s;
#pragma unroll
        for (int off = 1; off < 16; off <<= 1) n2 += __shfl_xor(n2, off, 16);
        float scale = (n2 / (1.f + n2)) / sqrtf(n2 + EPSF);
        vout[(b * 10 + tt) * 16 + t] = s * scale;
        if (last && t == 0) {
            float sv2 = n2 * scale * scale;
            out[b * 10 + tt] = sqrtf(sv2 + EPSF);
        }
    }
}

// ---- routing: bl (+)= sum_o u_hat * v -------------------------------------
__global__ __launch_bounds__(256) void k_route_b(const __bf16* __restrict__ uhT,
                                                 const float* __restrict__ vv,
                                                 float* __restrict__ bl,
                                                 int first) {
    __shared__ float vs[16];
    int b = blockIdx.x, tt = blockIdx.y;
    int t = threadIdx.x;
    if (t < 16) vs[t] = vv[(b * 10 + tt) * 16 + t];
    __syncthreads();
    const __bf16* uhb = uhT + ((size_t)b * 10 + tt) * 16384;
    float* blb = bl + (b * 10 + tt) * 1024;
    for (int p = t; p < 1024; p += 256) {
        float d = 0.f;
#pragma unroll
        for (int o = 0; o < 16; ++o) d = fmaf((float)uhb[o * 1024 + p], vs[o], d);
        blb[p] = first ? d : (blb[p] + d);
    }
}

// ---------------------------------------------------------------------------
extern "C" void kernel_launch(void* const* d_in, const int* in_sizes, int n_in,
                              void* d_out, int out_size, void* d_ws, size_t ws_size,
                              hipStream_t stream) {
    const float* x  = (const float*)d_in[0];
    const float* w1 = (const float*)d_in[1];
    const float* b1 = (const float*)d_in[2];
    const float* w2 = (const float*)d_in[3];
    const float* b2 = (const float*)d_in[4];
    const float* wc = (const float*)d_in[5];
    const float* bc = (const float*)d_in[6];
    const float* Wr = (const float*)d_in[7];
    float* out = (float*)d_out;
    float* ws  = (float*)d_ws;

    // workspace layout (float offsets)
    __bf16* w2b = (__bf16*)(ws);                  // 204800 bf16
    __bf16* wcb = (__bf16*)(ws + 102400);         // 524288 bf16
    __bf16* w1b = (__bf16*)(ws + 364544);         // 12288 bf16
    __bf16* h1n = (__bf16*)(ws + 375040);         // 14450688 bf16
    __bf16* h2n = (__bf16*)(ws + 7600384);        // 5914624 bf16
    float*  hcn = ws + 10557696;                  // 2097152 f
    float*  u   = ws + 12654848;                  // 2097152 f
    float*  bl  = ws + 14752000;                  // 655360 f
    float*  vv  = ws + 15407360;                  // 10240 f
    __bf16* uhT = (__bf16*)(ws + 375040);         // overlays h1n (dead by k_uhat)

    k_t_w1b<<<48, 256, 0, stream>>>(w1, w1b);
    k_t_w2b<<<800, 256, 0, stream>>>(w2, w2b);
    k_t_wcb<<<2048, 256, 0, stream>>>(wc, wcb);
    k_conv1_mfma<<<dim3(42, 2, 64), 256, 0, stream>>>(x, w1b, b1, h1n);
    k_conv2<<<dim3(8, 64), 192, 0, stream>>>(h1n, w2b, b2, h2n);
    k_convcaps<<<dim3(8, 64), 256, 0, stream>>>(h2n, wcb, bc, hcn);
    k_squash<<<dim3(64, 128), 256, 0, stream>>>(hcn, u);
    k_uhat<<<dim3(16, 10, 2), 256, 0, stream>>>(u, Wr, uhT);
    k_route_s<<<dim3(64, 10), 256, 0, stream>>>(uhT, bl, vv, out, 1, 0);
    k_route_b<<<dim3(64, 10), 256, 0, stream>>>(uhT, vv, bl, 1);
    k_route_s<<<dim3(64, 10), 256, 0, stream>>>(uhT, bl, vv, out, 0, 0);
    k_route_b<<<dim3(64, 10), 256, 0, stream>>>(uhT, vv, bl, 0);
    k_route_s<<<dim3(64, 10), 256, 0, stream>>>(uhT, bl, vv, out, 0, 1);
}

// Round 11
// 381.866 us; speedup vs baseline: 1.8919x; 1.1928x over previous
//
#include <hip/hip_runtime.h>
#include <hip/hip_bf16.h>
#include <math.h>

// ---------------------------------------------------------------------------
// GuoCapSAREncoder round 11: k_uhat restructured -- q indexes an o-quad so
// each thread hoists its Wr slice (bf16) into registers ONCE and reuses it
// across all 16 b's (kills the 16x Wr L2 amplification + VGPR=256 unroll bomb
// of round 10). u and Wr cast to bf16. Everything else frozen from round 10.
// ---------------------------------------------------------------------------

#define EPSF 1e-8f

typedef __bf16 bf16x8 __attribute__((ext_vector_type(8)));
typedef __bf16 bf16x4 __attribute__((ext_vector_type(4)));
typedef float floatx4 __attribute__((ext_vector_type(4)));
typedef float floatx16 __attribute__((ext_vector_type(16)));

// ---- weight transposes ----------------------------------------------------
__global__ __launch_bounds__(256) void k_t_w1b(const float* __restrict__ w1, __bf16* __restrict__ w1b) {
    int i = blockIdx.x * 256 + threadIdx.x;          // 12*128*8 = 12288
    if (i >= 12288) return;
    int kt = i >> 10, oc = (i >> 3) & 127, j = i & 7;
    int k = kt * 8 + j;
    w1b[i] = (__bf16)(k < 81 ? w1[oc * 81 + k] : 0.f);
}

__global__ __launch_bounds__(256) void k_t_w2b(const float* __restrict__ w2, __bf16* __restrict__ w2b) {
    int j = blockIdx.x * 256 + threadIdx.x;          // 204800
    if (j >= 204800) return;
    int khw = j / 8192, r2 = j & 8191;
    int oc = r2 >> 7, ic = r2 & 127;
    w2b[j] = (__bf16)w2[(oc * 128 + ic) * 25 + khw];
}

__global__ __launch_bounds__(256) void k_t_wcb(const float* __restrict__ wc, __bf16* __restrict__ wcb) {
    int j = blockIdx.x * 256 + threadIdx.x;          // 524288
    if (j >= 524288) return;
    int khw = j / 8192, r2 = j & 8191;
    int oc = r2 >> 6, ic = r2 & 63;
    wcb[j] = (__bf16)wc[(oc * 64 + ic) * 64 + khw];
}

// Wr fp32 -> bf16, layout unchanged [p][ts][o][i]
__global__ __launch_bounds__(256) void k_t_wrb(const float* __restrict__ Wr, __bf16* __restrict__ wrb) {
    int i = blockIdx.x * 256 + threadIdx.x;          // 5242880
    if (i >= 5242880) return;
    wrb[i] = (__bf16)Wr[i];
}

// ---- conv1 9x9 + ReLU + maxpool2 via MFMA -> h1n NHWC bf16 [b][42][42][128]
__global__ __launch_bounds__(256, 3) void k_conv1_mfma(const float* __restrict__ x,
                                                       const __bf16* __restrict__ w1b,
                                                       const float* __restrict__ b1,
                                                       __bf16* __restrict__ h1n) {
    __shared__ float xs[960];                        // 10 rows x 92 fp32 (+pad)
    __shared__ __bf16 Bl[18432];                     // 12kt x 2row x 96pos x 8j
    int py = blockIdx.x, ocg = blockIdx.y, b = blockIdx.z;
    int t = threadIdx.x;
    int lane = t & 63, w = t >> 6;
    int cc = lane & 15, q = lane >> 4;

    const float* xb = x + (size_t)b * 8464 + 2 * py * 92;
    for (int j = t; j < 920; j += 256) xs[j] = xb[j];

    int ocA = ocg * 64 + w * 16 + cc;
    bf16x8 af[3];
#pragma unroll
    for (int ks = 0; ks < 3; ++ks)
        af[ks] = *(const bf16x8*)(w1b + ((ks * 4 + q) * 128 + ocA) * 8);

    __syncthreads();

    if (t < 192) {
        int row = t / 96, pos = t - (t / 96) * 96;
        int sbase = row * 92 + pos;
        bool pvalid = pos < 84;
#pragma unroll
        for (int kt = 0; kt < 12; ++kt) {
            bf16x8 pk;
#pragma unroll
            for (int j = 0; j < 8; ++j) {
                int k = kt * 8 + j;
                int kh = k / 9, kw = k - kh * 9;
                float v = (pvalid && k < 81) ? xs[sbase + kh * 92 + kw] : 0.f;
                pk[j] = (__bf16)v;
            }
            *(bf16x8*)(Bl + ((kt * 2 + row) * 96 + pos) * 8) = pk;
        }
    }
    __syncthreads();

    floatx4 acc[2][6];
    const char* Bb = (const char*)Bl + cc * 16 + q * 3072;
#pragma unroll
    for (int rr = 0; rr < 2; ++rr)
#pragma unroll
        for (int n6 = 0; n6 < 6; ++n6) {
            floatx4 a = (floatx4){0.f, 0.f, 0.f, 0.f};
#pragma unroll
            for (int ks = 0; ks < 3; ++ks) {
                bf16x8 bf = *(const bf16x8*)(Bb + ks * 12288 + rr * 1536 + n6 * 256);
                a = __builtin_amdgcn_mfma_f32_16x16x32_bf16(af[ks], bf, a, 0, 0, 0);
            }
            acc[rr][n6] = a;
        }

    int oc0 = ocg * 64 + w * 16 + q * 4;
    float4 bv = *(const float4*)(b1 + oc0);
    size_t obase = (((size_t)b * 42 + py) * 42) * 128 + oc0;
#pragma unroll
    for (int n6 = 0; n6 < 6; ++n6) {
        bf16x4 pk;
#pragma unroll
        for (int r = 0; r < 4; ++r) {
            float vert = fmaxf(acc[0][n6][r], acc[1][n6][r]);
            float hz = fmaxf(vert, __shfl_xor(vert, 1, 64));
            float pooled = fmaxf(hz + ((const float*)&bv)[r], 0.f);
            pk[r] = (__bf16)pooled;
        }
        if ((cc & 1) == 0) {
            int px = n6 * 8 + (cc >> 1);
            if (px < 42)
                *(bf16x4*)(h1n + obase + (size_t)px * 128) = pk;
        }
    }
}

// ---- conv2 5x5 via MFMA 32x32x16: h1n NHWC -> h2n NHWC bf16 [b][38][38][64]
__global__ __launch_bounds__(192, 2) void k_conv2(const __bf16* __restrict__ h1n,
                                                  const __bf16* __restrict__ w2b,
                                                  const float* __restrict__ b2,
                                                  __bf16* __restrict__ h2n) {
    __shared__ __bf16 ins[25704];                    // 378 pos * 136 B = 51408 B
    int g = blockIdx.x, b = blockIdx.y;              // g in [0,8)
    int row0 = g * 5;
    int t = threadIdx.x;
    int lane = t & 63, w = t >> 6;                   // w in [0,3)
    int c32 = lane & 31, h = lane >> 5;
    int validp = (g < 7) ? 190 : 114;

    int baseN[2], posi[2];
#pragma unroll
    for (int nt = 0; nt < 2; ++nt) {
        int pi = (w * 2 + nt) * 32 + c32;
        int pc = pi < validp ? pi : validp - 1;
        int r = pc / 38, c = pc - r * 38;
        posi[nt] = pi;
        baseN[nt] = (r * 42 + c) * 136 + h * 16;
    }
    floatx16 acc[2][2];
#pragma unroll
    for (int mt = 0; mt < 2; ++mt)
#pragma unroll
        for (int nt = 0; nt < 2; ++nt)
#pragma unroll
            for (int i = 0; i < 16; ++i) acc[mt][nt][i] = 0.f;

    for (int ic0 = 0; ic0 < 128; ic0 += 64) {
        __syncthreads();
        for (int j = t; j < 3024; j += 192) {        // 9 rows x 42 x 8 sb
            int lr = j / 336, rem = j - lr * 336;
            int ix = rem >> 3, sb = rem & 7;
            int rg = row0 + lr; if (rg > 41) rg = 41;
            const uint4* src = (const uint4*)(h1n + ((((size_t)b * 42 + rg) * 42 + ix) * 128 + ic0 + sb * 8));
            int pos = lr * 42 + ix;
            *(uint4*)((char*)ins + (size_t)pos * 136 + sb * 16) = *src;
        }
        __syncthreads();
#pragma unroll
        for (int khw = 0; khw < 25; ++khw) {
            int kh = khw / 5, kw = khw - kh * 5;
            int doff = (kh * 42 + kw) * 136;
#pragma unroll
            for (int ks = 0; ks < 4; ++ks) {
                bf16x8 a0 = *(const bf16x8*)(w2b + (size_t)(khw * 64 + c32) * 128 + ic0 + ks * 16 + h * 8);
                bf16x8 a1 = *(const bf16x8*)(w2b + (size_t)(khw * 64 + 32 + c32) * 128 + ic0 + ks * 16 + h * 8);
#pragma unroll
                for (int nt = 0; nt < 2; ++nt) {
                    bf16x8 bfr = *(const bf16x8*)((char*)ins + baseN[nt] + doff + ks * 32);
                    acc[0][nt] = __builtin_amdgcn_mfma_f32_32x32x16_bf16(a0, bfr, acc[0][nt], 0, 0, 0);
                    acc[1][nt] = __builtin_amdgcn_mfma_f32_32x32x16_bf16(a1, bfr, acc[1][nt], 0, 0, 0);
                }
            }
        }
    }
#pragma unroll
    for (int nt = 0; nt < 2; ++nt) {
        int pi = posi[nt];
        if (pi < validp) {
            int r = pi / 38, c = pi - r * 38;
            int oh = row0 + r;
            size_t obase = (((size_t)b * 38 + oh) * 38 + c) * 64;
#pragma unroll
            for (int mt = 0; mt < 2; ++mt) {
#pragma unroll
                for (int g2 = 0; g2 < 4; ++g2) {
                    int oc0 = mt * 32 + g2 * 8 + h * 4;
                    float4 bv = *(const float4*)(b2 + oc0);
                    bf16x4 pk;
                    pk.x = (__bf16)(acc[mt][nt][g2 * 4 + 0] + bv.x);
                    pk.y = (__bf16)(acc[mt][nt][g2 * 4 + 1] + bv.y);
                    pk.z = (__bf16)(acc[mt][nt][g2 * 4 + 2] + bv.z);
                    pk.w = (__bf16)(acc[mt][nt][g2 * 4 + 3] + bv.w);
                    *(bf16x4*)(h2n + obase + oc0) = pk;
                }
            }
        }
    }
}

// ---- caps conv 8x8 s2 via MFMA: h2n NHWC bf16 -> hcn NHWC fp32 ------------
__global__ __launch_bounds__(256, 2) void k_convcaps(const __bf16* __restrict__ h2n,
                                                     const __bf16* __restrict__ wcb,
                                                     const float* __restrict__ bc,
                                                     float* __restrict__ hcn) {
    __shared__ __bf16 ins[13680];                    // 380 * 72 B = 27360 B
    int g = blockIdx.x, b = blockIdx.y;              // g in [0,8)
    int t = threadIdx.x;
    int lane = t & 63, w = t >> 6;
    int cc = lane & 15, q = lane >> 4;

    floatx4 acc[2][2];
#pragma unroll
    for (int mt = 0; mt < 2; ++mt)
#pragma unroll
        for (int nt = 0; nt < 2; ++nt) acc[mt][nt] = (floatx4){0.f, 0.f, 0.f, 0.f};

    int ocA = w * 32 + cc;
    int rbase = cc * 72 + q * 16;
    for (int ic0 = 0; ic0 < 64; ic0 += 32) {
        __syncthreads();
        for (int j = t; j < 1520; j += 256) {
            int r = j / 152, rem = j - r * 152;
            int c = rem >> 2, s = rem & 3;
            const uint4* src = (const uint4*)(h2n + ((((size_t)b * 38 + 4 * g + r) * 38 + c) * 64 + ic0 + s * 8));
            int X = (r * 2 + (c & 1)) * 19 + (c >> 1);
            *(uint4*)((char*)ins + X * 72 + s * 16) = *src;
        }
        __syncthreads();
#pragma unroll
        for (int khw = 0; khw < 64; ++khw) {
            int kh = khw >> 3, kw = khw & 7;
            int par = kw & 1, k2 = kw >> 1;
            bf16x8 a0 = *(const bf16x8*)(wcb + (size_t)(khw * 128 + ocA) * 64 + ic0 + q * 8);
            bf16x8 a1 = *(const bf16x8*)(wcb + (size_t)(khw * 128 + ocA + 16) * 64 + ic0 + q * 8);
#pragma unroll
            for (int nt = 0; nt < 2; ++nt) {
                int doff = (((2 * nt + kh) * 2 + par) * 19 + k2) * 72;
                bf16x8 bfr = *(const bf16x8*)((char*)ins + rbase + doff);
                acc[0][nt] = __builtin_amdgcn_mfma_f32_16x16x32_bf16(a0, bfr, acc[0][nt], 0, 0, 0);
                acc[1][nt] = __builtin_amdgcn_mfma_f32_16x16x32_bf16(a1, bfr, acc[1][nt], 0, 0, 0);
            }
        }
    }
#pragma unroll
    for (int mt = 0; mt < 2; ++mt) {
        int oc0 = w * 32 + mt * 16 + q * 4;
        float4 bv = *(const float4*)(bc + oc0);
#pragma unroll
        for (int nt = 0; nt < 2; ++nt) {
            int oh = 2 * g + nt, ow = cc;
            float4 st;
            st.x = acc[mt][nt][0] + bv.x;
            st.y = acc[mt][nt][1] + bv.y;
            st.z = acc[mt][nt][2] + bv.z;
            st.w = acc[mt][nt][3] + bv.w;
            *(float4*)(hcn + (((size_t)b * 256 + oh * 16 + ow) * 128 + oc0)) = st;
        }
    }
}

// ---- primary-capsule reorder + squash: hcn NHWC -> ub bf16 [64,1024,32] ---
__global__ __launch_bounds__(256) void k_squash(const float* __restrict__ hcn,
                                                __bf16* __restrict__ ub) {
    int b = blockIdx.x, capg = blockIdx.y;
    int t = threadIdx.x;
    int capl = t >> 5, i = t & 31;
    int cap = capg * 8 + capl;
    int ct = cap >> 8, rem = cap & 255;
    float val = hcn[((size_t)b * 256 + rem) * 128 + ct * 32 + i];
    float s = val * val;
#pragma unroll
    for (int off = 1; off < 32; off <<= 1) s += __shfl_xor(s, off, 64);
    float scale = (s / (1.f + s)) / sqrtf(s + EPSF);
    ub[((size_t)b * 1024 + cap) * 32 + i] = (__bf16)(val * scale);
}

// ---- u_hat: ub bf16 [64,1024,32] x wrb bf16 [1024,10,16,32] -> uhT bf16 ---
// grid (16 pt, 10 ts, 4 bz). Thread: p = t&63 (lane), q = t>>6 = o-quad.
// Wr slice (4 o x 32 i bf16 = 64 VGPR) hoisted ONCE, reused across 16 b's.
__global__ __launch_bounds__(256, 2) void k_uhat(const __bf16* __restrict__ ub,
                                                 const __bf16* __restrict__ wrb,
                                                 __bf16* __restrict__ uhT) {
    int pt = blockIdx.x, ts = blockIdx.y, bz = blockIdx.z;
    int t = threadIdx.x;
    int p = pt * 64 + (t & 63);
    int q = t >> 6;
    bf16x8 wf[4][4];
#pragma unroll
    for (int o4 = 0; o4 < 4; ++o4)
#pragma unroll
        for (int j = 0; j < 4; ++j)
            wf[o4][j] = *(const bf16x8*)(wrb + (((size_t)p * 10 + ts) * 16 + q * 4 + o4) * 32 + j * 8);
#pragma unroll 1
    for (int bi = 0; bi < 16; ++bi) {
        int b = bz * 16 + bi;
        bf16x8 uf[4];
        const bf16x8* up = (const bf16x8*)(ub + ((size_t)b * 1024 + p) * 32);
#pragma unroll
        for (int j = 0; j < 4; ++j) uf[j] = up[j];
#pragma unroll
        for (int o4 = 0; o4 < 4; ++o4) {
            float s = 0.f;
#pragma unroll
            for (int j = 0; j < 4; ++j)
#pragma unroll
                for (int e = 0; e < 8; ++e)
                    s = fmaf((float)uf[j][e], (float)wf[o4][j][e], s);
            uhT[(((size_t)b * 10 + ts) * 16 + q * 4 + o4) * 1024 + p] = (__bf16)s;
        }
    }
}

// ---- routing: s = sum_p softmax(bl)_pt * u_hat ; v = squash(s) ------------
__global__ __launch_bounds__(256) void k_route_s(const __bf16* __restrict__ uhT,
                                                 const float* __restrict__ bl,
                                                 float* __restrict__ vout,
                                                 float* __restrict__ out,
                                                 int first, int last) {
    __shared__ float sred[4][16];
    int b = blockIdx.x, tt = blockIdx.y;
    int t = threadIdx.x;
    float acc[16];
#pragma unroll
    for (int o = 0; o < 16; ++o) acc[o] = 0.f;
    const float* blb = bl + b * 10240;
    const __bf16* uhb = uhT + ((size_t)b * 10 + tt) * 16384;
    for (int p = t; p < 1024; p += 256) {
        float c;
        if (first) {
            c = 0.1f;
        } else {
            float den = 0.f, et = 0.f;
#pragma unroll
            for (int tp = 0; tp < 10; ++tp) {
                float e = expf(blb[tp * 1024 + p]);
                den += e;
                if (tp == tt) et = e;
            }
            c = et / den;
        }
#pragma unroll
        for (int o = 0; o < 16; ++o)
            acc[o] = fmaf(c, (float)uhb[o * 1024 + p], acc[o]);
    }
    int lane = t & 63, wid = t >> 6;
#pragma unroll
    for (int o = 0; o < 16; ++o) {
        float v = acc[o];
#pragma unroll
        for (int off = 32; off >= 1; off >>= 1) v += __shfl_xor(v, off, 64);
        if (lane == 0) sred[wid][o] = v;
    }
    __syncthreads();
    if (t < 16) {
        float s = (sred[0][t] + sred[1][t]) + (sred[2][t] + sred[3][t]);
        float n2 = s * s;
#pragma unroll
        for (int off = 1; off < 16; off <<= 1) n2 += __shfl_xor(n2, off, 16);
        float scale = (n2 / (1.f + n2)) / sqrtf(n2 + EPSF);
        vout[(b * 10 + tt) * 16 + t] = s * scale;
        if (last && t == 0) {
            float sv2 = n2 * scale * scale;
            out[b * 10 + tt] = sqrtf(sv2 + EPSF);
        }
    }
}

// ---- routing: bl (+)= sum_o u_hat * v -------------------------------------
__global__ __launch_bounds__(256) void k_route_b(const __bf16* __restrict__ uhT,
                                                 const float* __restrict__ vv,
                                                 float* __restrict__ bl,
                                                 int first) {
    __shared__ float vs[16];
    int b = blockIdx.x, tt = blockIdx.y;
    int t = threadIdx.x;
    if (t < 16) vs[t] = vv[(b * 10 + tt) * 16 + t];
    __syncthreads();
    const __bf16* uhb = uhT + ((size_t)b * 10 + tt) * 16384;
    float* blb = bl + (b * 10 + tt) * 1024;
    for (int p = t; p < 1024; p += 256) {
        float d = 0.f;
#pragma unroll
        for (int o = 0; o < 16; ++o) d = fmaf((float)uhb[o * 1024 + p], vs[o], d);
        blb[p] = first ? d : (blb[p] + d);
    }
}

// ---------------------------------------------------------------------------
extern "C" void kernel_launch(void* const* d_in, const int* in_sizes, int n_in,
                              void* d_out, int out_size, void* d_ws, size_t ws_size,
                              hipStream_t stream) {
    const float* x  = (const float*)d_in[0];
    const float* w1 = (const float*)d_in[1];
    const float* b1 = (const float*)d_in[2];
    const float* w2 = (const float*)d_in[3];
    const float* b2 = (const float*)d_in[4];
    const float* wc = (const float*)d_in[5];
    const float* bc = (const float*)d_in[6];
    const float* Wr = (const float*)d_in[7];
    float* out = (float*)d_out;
    float* ws  = (float*)d_ws;

    // workspace layout (float offsets)
    __bf16* w2b = (__bf16*)(ws);                  // 204800 bf16
    __bf16* wcb = (__bf16*)(ws + 102400);         // 524288 bf16
    __bf16* w1b = (__bf16*)(ws + 364544);         // 12288 bf16
    __bf16* h1n = (__bf16*)(ws + 375040);         // 14450688 bf16
    __bf16* h2n = (__bf16*)(ws + 7600384);        // 5914624 bf16
    float*  hcn = ws + 10557696;                  // 2097152 f
    __bf16* ub  = (__bf16*)(ws + 12654848);       // 2097152 bf16
    float*  bl  = ws + 14752000;                  // 655360 f
    float*  vv  = ws + 15407360;                  // 10240 f
    __bf16* wrb = (__bf16*)(ws + 15417600);       // 5242880 bf16 -> end 18039040 f (72 MB)
    __bf16* uhT = (__bf16*)(ws + 375040);         // overlays h1n (dead by k_uhat)

    k_t_w1b<<<48, 256, 0, stream>>>(w1, w1b);
    k_t_w2b<<<800, 256, 0, stream>>>(w2, w2b);
    k_t_wcb<<<2048, 256, 0, stream>>>(wc, wcb);
    k_t_wrb<<<20480, 256, 0, stream>>>(Wr, wrb);
    k_conv1_mfma<<<dim3(42, 2, 64), 256, 0, stream>>>(x, w1b, b1, h1n);
    k_conv2<<<dim3(8, 64), 192, 0, stream>>>(h1n, w2b, b2, h2n);
    k_convcaps<<<dim3(8, 64), 256, 0, stream>>>(h2n, wcb, bc, hcn);
    k_squash<<<dim3(64, 128), 256, 0, stream>>>(hcn, ub);
    k_uhat<<<dim3(16, 10, 4), 256, 0, stream>>>(ub, wrb, uhT);
    k_route_s<<<dim3(64, 10), 256, 0, stream>>>(uhT, bl, vv, out, 1, 0);
    k_route_b<<<dim3(64, 10), 256, 0, stream>>>(uhT, vv, bl, 1);
    k_route_s<<<dim3(64, 10), 256, 0, stream>>>(uhT, bl, vv, out, 0, 0);
    k_route_b<<<dim3(64, 10), 256, 0, stream>>>(uhT, vv, bl, 0);
    k_route_s<<<dim3(64, 10), 256, 0, stream>>>(uhT, bl, vv, out, 0, 1);
}

// Round 12
// 357.575 us; speedup vs baseline: 2.0204x; 1.0679x over previous
//
#include <hip/hip_runtime.h>
#include <hip/hip_bf16.h>
#include <math.h>

// ---------------------------------------------------------------------------
// GuoCapSAREncoder round 12: convcaps rewritten with 32x32x16 MFMA, wave =
// one capsule type (32 oc), squash FUSED into the epilogue (norm = per-lane
// reg sum + shfl_xor(32)) writing ub bf16 directly. Kills hcn's 57 MB RMW
// write amplification + the k_squash launch. Everything else frozen from r11.
// ---------------------------------------------------------------------------

#define EPSF 1e-8f

typedef __bf16 bf16x8 __attribute__((ext_vector_type(8)));
typedef __bf16 bf16x4 __attribute__((ext_vector_type(4)));
typedef float floatx4 __attribute__((ext_vector_type(4)));
typedef float floatx16 __attribute__((ext_vector_type(16)));

// ---- weight transposes ----------------------------------------------------
__global__ __launch_bounds__(256) void k_t_w1b(const float* __restrict__ w1, __bf16* __restrict__ w1b) {
    int i = blockIdx.x * 256 + threadIdx.x;          // 12*128*8 = 12288
    if (i >= 12288) return;
    int kt = i >> 10, oc = (i >> 3) & 127, j = i & 7;
    int k = kt * 8 + j;
    w1b[i] = (__bf16)(k < 81 ? w1[oc * 81 + k] : 0.f);
}

__global__ __launch_bounds__(256) void k_t_w2b(const float* __restrict__ w2, __bf16* __restrict__ w2b) {
    int j = blockIdx.x * 256 + threadIdx.x;          // 204800
    if (j >= 204800) return;
    int khw = j / 8192, r2 = j & 8191;
    int oc = r2 >> 7, ic = r2 & 127;
    w2b[j] = (__bf16)w2[(oc * 128 + ic) * 25 + khw];
}

__global__ __launch_bounds__(256) void k_t_wcb(const float* __restrict__ wc, __bf16* __restrict__ wcb) {
    int j = blockIdx.x * 256 + threadIdx.x;          // 524288
    if (j >= 524288) return;
    int khw = j / 8192, r2 = j & 8191;
    int oc = r2 >> 6, ic = r2 & 63;
    wcb[j] = (__bf16)wc[(oc * 64 + ic) * 64 + khw];
}

__global__ __launch_bounds__(256) void k_t_wrb(const float* __restrict__ Wr, __bf16* __restrict__ wrb) {
    int i = blockIdx.x * 256 + threadIdx.x;          // 5242880
    if (i >= 5242880) return;
    wrb[i] = (__bf16)Wr[i];
}

// ---- conv1 9x9 + ReLU + maxpool2 via MFMA -> h1n NHWC bf16 [b][42][42][128]
__global__ __launch_bounds__(256, 3) void k_conv1_mfma(const float* __restrict__ x,
                                                       const __bf16* __restrict__ w1b,
                                                       const float* __restrict__ b1,
                                                       __bf16* __restrict__ h1n) {
    __shared__ float xs[960];                        // 10 rows x 92 fp32 (+pad)
    __shared__ __bf16 Bl[18432];                     // 12kt x 2row x 96pos x 8j
    int py = blockIdx.x, ocg = blockIdx.y, b = blockIdx.z;
    int t = threadIdx.x;
    int lane = t & 63, w = t >> 6;
    int cc = lane & 15, q = lane >> 4;

    const float* xb = x + (size_t)b * 8464 + 2 * py * 92;
    for (int j = t; j < 920; j += 256) xs[j] = xb[j];

    int ocA = ocg * 64 + w * 16 + cc;
    bf16x8 af[3];
#pragma unroll
    for (int ks = 0; ks < 3; ++ks)
        af[ks] = *(const bf16x8*)(w1b + ((ks * 4 + q) * 128 + ocA) * 8);

    __syncthreads();

    if (t < 192) {
        int row = t / 96, pos = t - (t / 96) * 96;
        int sbase = row * 92 + pos;
        bool pvalid = pos < 84;
#pragma unroll
        for (int kt = 0; kt < 12; ++kt) {
            bf16x8 pk;
#pragma unroll
            for (int j = 0; j < 8; ++j) {
                int k = kt * 8 + j;
                int kh = k / 9, kw = k - kh * 9;
                float v = (pvalid && k < 81) ? xs[sbase + kh * 92 + kw] : 0.f;
                pk[j] = (__bf16)v;
            }
            *(bf16x8*)(Bl + ((kt * 2 + row) * 96 + pos) * 8) = pk;
        }
    }
    __syncthreads();

    floatx4 acc[2][6];
    const char* Bb = (const char*)Bl + cc * 16 + q * 3072;
#pragma unroll
    for (int rr = 0; rr < 2; ++rr)
#pragma unroll
        for (int n6 = 0; n6 < 6; ++n6) {
            floatx4 a = (floatx4){0.f, 0.f, 0.f, 0.f};
#pragma unroll
            for (int ks = 0; ks < 3; ++ks) {
                bf16x8 bf = *(const bf16x8*)(Bb + ks * 12288 + rr * 1536 + n6 * 256);
                a = __builtin_amdgcn_mfma_f32_16x16x32_bf16(af[ks], bf, a, 0, 0, 0);
            }
            acc[rr][n6] = a;
        }

    int oc0 = ocg * 64 + w * 16 + q * 4;
    float4 bv = *(const float4*)(b1 + oc0);
    size_t obase = (((size_t)b * 42 + py) * 42) * 128 + oc0;
#pragma unroll
    for (int n6 = 0; n6 < 6; ++n6) {
        bf16x4 pk;
#pragma unroll
        for (int r = 0; r < 4; ++r) {
            float vert = fmaxf(acc[0][n6][r], acc[1][n6][r]);
            float hz = fmaxf(vert, __shfl_xor(vert, 1, 64));
            float pooled = fmaxf(hz + ((const float*)&bv)[r], 0.f);
            pk[r] = (__bf16)pooled;
        }
        if ((cc & 1) == 0) {
            int px = n6 * 8 + (cc >> 1);
            if (px < 42)
                *(bf16x4*)(h1n + obase + (size_t)px * 128) = pk;
        }
    }
}

// ---- conv2 5x5 via MFMA 32x32x16: h1n NHWC -> h2n NHWC bf16 [b][38][38][64]
__global__ __launch_bounds__(192, 2) void k_conv2(const __bf16* __restrict__ h1n,
                                                  const __bf16* __restrict__ w2b,
                                                  const float* __restrict__ b2,
                                                  __bf16* __restrict__ h2n) {
    __shared__ __bf16 ins[25704];                    // 378 pos * 136 B = 51408 B
    int g = blockIdx.x, b = blockIdx.y;              // g in [0,8)
    int row0 = g * 5;
    int t = threadIdx.x;
    int lane = t & 63, w = t >> 6;                   // w in [0,3)
    int c32 = lane & 31, h = lane >> 5;
    int validp = (g < 7) ? 190 : 114;

    int baseN[2], posi[2];
#pragma unroll
    for (int nt = 0; nt < 2; ++nt) {
        int pi = (w * 2 + nt) * 32 + c32;
        int pc = pi < validp ? pi : validp - 1;
        int r = pc / 38, c = pc - r * 38;
        posi[nt] = pi;
        baseN[nt] = (r * 42 + c) * 136 + h * 16;
    }
    floatx16 acc[2][2];
#pragma unroll
    for (int mt = 0; mt < 2; ++mt)
#pragma unroll
        for (int nt = 0; nt < 2; ++nt)
#pragma unroll
            for (int i = 0; i < 16; ++i) acc[mt][nt][i] = 0.f;

    for (int ic0 = 0; ic0 < 128; ic0 += 64) {
        __syncthreads();
        for (int j = t; j < 3024; j += 192) {        // 9 rows x 42 x 8 sb
            int lr = j / 336, rem = j - lr * 336;
            int ix = rem >> 3, sb = rem & 7;
            int rg = row0 + lr; if (rg > 41) rg = 41;
            const uint4* src = (const uint4*)(h1n + ((((size_t)b * 42 + rg) * 42 + ix) * 128 + ic0 + sb * 8));
            int pos = lr * 42 + ix;
            *(uint4*)((char*)ins + (size_t)pos * 136 + sb * 16) = *src;
        }
        __syncthreads();
#pragma unroll
        for (int khw = 0; khw < 25; ++khw) {
            int kh = khw / 5, kw = khw - kh * 5;
            int doff = (kh * 42 + kw) * 136;
#pragma unroll
            for (int ks = 0; ks < 4; ++ks) {
                bf16x8 a0 = *(const bf16x8*)(w2b + (size_t)(khw * 64 + c32) * 128 + ic0 + ks * 16 + h * 8);
                bf16x8 a1 = *(const bf16x8*)(w2b + (size_t)(khw * 64 + 32 + c32) * 128 + ic0 + ks * 16 + h * 8);
#pragma unroll
                for (int nt = 0; nt < 2; ++nt) {
                    bf16x8 bfr = *(const bf16x8*)((char*)ins + baseN[nt] + doff + ks * 32);
                    acc[0][nt] = __builtin_amdgcn_mfma_f32_32x32x16_bf16(a0, bfr, acc[0][nt], 0, 0, 0);
                    acc[1][nt] = __builtin_amdgcn_mfma_f32_32x32x16_bf16(a1, bfr, acc[1][nt], 0, 0, 0);
                }
            }
        }
    }
#pragma unroll
    for (int nt = 0; nt < 2; ++nt) {
        int pi = posi[nt];
        if (pi < validp) {
            int r = pi / 38, c = pi - r * 38;
            int oh = row0 + r;
            size_t obase = (((size_t)b * 38 + oh) * 38 + c) * 64;
#pragma unroll
            for (int mt = 0; mt < 2; ++mt) {
#pragma unroll
                for (int g2 = 0; g2 < 4; ++g2) {
                    int oc0 = mt * 32 + g2 * 8 + h * 4;
                    float4 bv = *(const float4*)(b2 + oc0);
                    bf16x4 pk;
                    pk.x = (__bf16)(acc[mt][nt][g2 * 4 + 0] + bv.x);
                    pk.y = (__bf16)(acc[mt][nt][g2 * 4 + 1] + bv.y);
                    pk.z = (__bf16)(acc[mt][nt][g2 * 4 + 2] + bv.z);
                    pk.w = (__bf16)(acc[mt][nt][g2 * 4 + 3] + bv.w);
                    *(bf16x4*)(h2n + obase + oc0) = pk;
                }
            }
        }
    }
}

// ---- caps conv 8x8 s2 via MFMA 32x32x16 + FUSED squash -> ub bf16 ---------
// Block = (g in [0,8), b): 2 output rows (32 pos = 1 N-tile). Wave = capsule
// type ct (32-oc M-tile). D col = pos, D row = component i = g2*8 + h*4 + j.
// Squash norm = per-lane sum of 16 reg^2 + shfl_xor(32). Writes ub directly.
__global__ __launch_bounds__(256, 4) void k_convcaps(const __bf16* __restrict__ h2n,
                                                     const __bf16* __restrict__ wcb,
                                                     const float* __restrict__ bc,
                                                     __bf16* __restrict__ ub) {
    __shared__ __bf16 ins[13680];                    // 380 * 72 B = 27360 B
    int g = blockIdx.x, b = blockIdx.y;              // g in [0,8)
    int t = threadIdx.x;
    int lane = t & 63, ct = t >> 6;                  // wave = capsule type
    int c32 = lane & 31, h = lane >> 5;
    int rloc = c32 >> 4, cx = c32 & 15;

    floatx16 acc;
#pragma unroll
    for (int i = 0; i < 16; ++i) acc[i] = 0.f;

    int Bbase = (76 * rloc + cx) * 72 + h * 16;      // lane byte base in slab
    for (int ic0 = 0; ic0 < 64; ic0 += 32) {
        __syncthreads();
        for (int j = t; j < 1520; j += 256) {        // 10 rows x 38 cols x 4 s
            int r = j / 152, rem = j - r * 152;
            int c = rem >> 2, s = rem & 3;
            const uint4* src = (const uint4*)(h2n + ((((size_t)b * 38 + 4 * g + r) * 38 + c) * 64 + ic0 + s * 8));
            int X = (r * 2 + (c & 1)) * 19 + (c >> 1);
            *(uint4*)((char*)ins + X * 72 + s * 16) = *src;
        }
        __syncthreads();
#pragma unroll
        for (int khw = 0; khw < 64; ++khw) {
            int kh = khw >> 3, kw = khw & 7;
            int par = kw & 1, k2 = kw >> 1;
            int doff = ((kh * 2 + par) * 19 + k2) * 72;
#pragma unroll
            for (int ks = 0; ks < 2; ++ks) {
                bf16x8 af = *(const bf16x8*)(wcb + (size_t)(khw * 128 + ct * 32 + c32) * 64 + ic0 + ks * 16 + h * 8);
                bf16x8 bfr = *(const bf16x8*)((char*)ins + Bbase + doff + ks * 32);
                acc = __builtin_amdgcn_mfma_f32_32x32x16_bf16(af, bfr, acc, 0, 0, 0);
            }
        }
    }
    // fused bias + squash
    float vals[16];
    float n2p = 0.f;
#pragma unroll
    for (int g2 = 0; g2 < 4; ++g2) {
        float4 bv = *(const float4*)(bc + ct * 32 + g2 * 8 + h * 4);
#pragma unroll
        for (int j = 0; j < 4; ++j) {
            float v = acc[g2 * 4 + j] + ((const float*)&bv)[j];
            vals[g2 * 4 + j] = v;
            n2p = fmaf(v, v, n2p);
        }
    }
    float n2 = n2p + __shfl_xor(n2p, 32, 64);
    float scale = (n2 / (1.f + n2)) / sqrtf(n2 + EPSF);
    int pos = (2 * g + rloc) * 16 + cx;              // y*16 + x
    __bf16* dst = ub + (((size_t)b * 1024 + ct * 256 + pos) * 32);
#pragma unroll
    for (int g2 = 0; g2 < 4; ++g2) {
        bf16x4 pk;
        pk.x = (__bf16)(vals[g2 * 4 + 0] * scale);
        pk.y = (__bf16)(vals[g2 * 4 + 1] * scale);
        pk.z = (__bf16)(vals[g2 * 4 + 2] * scale);
        pk.w = (__bf16)(vals[g2 * 4 + 3] * scale);
        *(bf16x4*)(dst + g2 * 8 + h * 4) = pk;
    }
}

// ---- u_hat: ub bf16 [64,1024,32] x wrb bf16 [1024,10,16,32] -> uhT bf16 ---
__global__ __launch_bounds__(256, 2) void k_uhat(const __bf16* __restrict__ ub,
                                                 const __bf16* __restrict__ wrb,
                                                 __bf16* __restrict__ uhT) {
    int pt = blockIdx.x, ts = blockIdx.y, bz = blockIdx.z;
    int t = threadIdx.x;
    int p = pt * 64 + (t & 63);
    int q = t >> 6;
    bf16x8 wf[4][4];
#pragma unroll
    for (int o4 = 0; o4 < 4; ++o4)
#pragma unroll
        for (int j = 0; j < 4; ++j)
            wf[o4][j] = *(const bf16x8*)(wrb + (((size_t)p * 10 + ts) * 16 + q * 4 + o4) * 32 + j * 8);
#pragma unroll 1
    for (int bi = 0; bi < 16; ++bi) {
        int b = bz * 16 + bi;
        bf16x8 uf[4];
        const bf16x8* up = (const bf16x8*)(ub + ((size_t)b * 1024 + p) * 32);
#pragma unroll
        for (int j = 0; j < 4; ++j) uf[j] = up[j];
#pragma unroll
        for (int o4 = 0; o4 < 4; ++o4) {
            float s = 0.f;
#pragma unroll
            for (int j = 0; j < 4; ++j)
#pragma unroll
                for (int e = 0; e < 8; ++e)
                    s = fmaf((float)uf[j][e], (float)wf[o4][j][e], s);
            uhT[(((size_t)b * 10 + ts) * 16 + q * 4 + o4) * 1024 + p] = (__bf16)s;
        }
    }
}

// ---- routing: s = sum_p softmax(bl)_pt * u_hat ; v = squash(s) ------------
__global__ __launch_bounds__(256) void k_route_s(const __bf16* __restrict__ uhT,
                                                 const float* __restrict__ bl,
                                                 float* __restrict__ vout,
                                                 float* __restrict__ out,
                                                 int first, int last) {
    __shared__ float sred[4][16];
    int b = blockIdx.x, tt = blockIdx.y;
    int t = threadIdx.x;
    float acc[16];
#pragma unroll
    for (int o = 0; o < 16; ++o) acc[o] = 0.f;
    const float* blb = bl + b * 10240;
    const __bf16* uhb = uhT + ((size_t)b * 10 + tt) * 16384;
    for (int p = t; p < 1024; p += 256) {
        float c;
        if (first) {
            c = 0.1f;
        } else {
            float den = 0.f, et = 0.f;
#pragma unroll
            for (int tp = 0; tp < 10; ++tp) {
                float e = expf(blb[tp * 1024 + p]);
                den += e;
                if (tp == tt) et = e;
            }
            c = et / den;
        }
#pragma unroll
        for (int o = 0; o < 16; ++o)
            acc[o] = fmaf(c, (float)uhb[o * 1024 + p], acc[o]);
    }
    int lane = t & 63, wid = t >> 6;
#pragma unroll
    for (int o = 0; o < 16; ++o) {
        float v = acc[o];
#pragma unroll
        for (int off = 32; off >= 1; off >>= 1) v += __shfl_xor(v, off, 64);
        if (lane == 0) sred[wid][o] = v;
    }
    __syncthreads();
    if (t < 16) {
        float s = (sred[0][t] + sred[1][t]) + (sred[2][t] + sred[3][t]);
        float n2 = s * s;
#pragma unroll
        for (int off = 1; off < 16; off <<= 1) n2 += __shfl_xor(n2, off, 16);
        float scale = (n2 / (1.f + n2)) / sqrtf(n2 + EPSF);
        vout[(b * 10 + tt) * 16 + t] = s * scale;
        if (last && t == 0) {
            float sv2 = n2 * scale * scale;
            out[b * 10 + tt] = sqrtf(sv2 + EPSF);
        }
    }
}

// ---- routing: bl (+)= sum_o u_hat * v -------------------------------------
__global__ __launch_bounds__(256) void k_route_b(const __bf16* __restrict__ uhT,
                                                 const float* __restrict__ vv,
                                                 float* __restrict__ bl,
                                                 int first) {
    __shared__ float vs[16];
    int b = blockIdx.x, tt = blockIdx.y;
    int t = threadIdx.x;
    if (t < 16) vs[t] = vv[(b * 10 + tt) * 16 + t];
    __syncthreads();
    const __bf16* uhb = uhT + ((size_t)b * 10 + tt) * 16384;
    float* blb = bl + (b * 10 + tt) * 1024;
    for (int p = t; p < 1024; p += 256) {
        float d = 0.f;
#pragma unroll
        for (int o = 0; o < 16; ++o) d = fmaf((float)uhb[o * 1024 + p], vs[o], d);
        blb[p] = first ? d : (blb[p] + d);
    }
}

// ---------------------------------------------------------------------------
extern "C" void kernel_launch(void* const* d_in, const int* in_sizes, int n_in,
                              void* d_out, int out_size, void* d_ws, size_t ws_size,
                              hipStream_t stream) {
    const float* x  = (const float*)d_in[0];
    const float* w1 = (const float*)d_in[1];
    const float* b1 = (const float*)d_in[2];
    const float* w2 = (const float*)d_in[3];
    const float* b2 = (const float*)d_in[4];
    const float* wc = (const float*)d_in[5];
    const float* bc = (const float*)d_in[6];
    const float* Wr = (const float*)d_in[7];
    float* out = (float*)d_out;
    float* ws  = (float*)d_ws;

    // workspace layout (float offsets)
    __bf16* w2b = (__bf16*)(ws);                  // 204800 bf16
    __bf16* wcb = (__bf16*)(ws + 102400);         // 524288 bf16
    __bf16* w1b = (__bf16*)(ws + 364544);         // 12288 bf16
    __bf16* h1n = (__bf16*)(ws + 375040);         // 14450688 bf16
    __bf16* h2n = (__bf16*)(ws + 7600384);        // 5914624 bf16
    __bf16* ub  = (__bf16*)(ws + 12654848);       // 2097152 bf16
    float*  bl  = ws + 14752000;                  // 655360 f
    float*  vv  = ws + 15407360;                  // 10240 f
    __bf16* wrb = (__bf16*)(ws + 15417600);       // 5242880 bf16
    __bf16* uhT = (__bf16*)(ws + 375040);         // overlays h1n (dead by k_uhat)

    k_t_w1b<<<48, 256, 0, stream>>>(w1, w1b);
    k_t_w2b<<<800, 256, 0, stream>>>(w2, w2b);
    k_t_wcb<<<2048, 256, 0, stream>>>(wc, wcb);
    k_t_wrb<<<20480, 256, 0, stream>>>(Wr, wrb);
    k_conv1_mfma<<<dim3(42, 2, 64), 256, 0, stream>>>(x, w1b, b1, h1n);
    k_conv2<<<dim3(8, 64), 192, 0, stream>>>(h1n, w2b, b2, h2n);
    k_convcaps<<<dim3(8, 64), 256, 0, stream>>>(h2n, wcb, bc, ub);
    k_uhat<<<dim3(16, 10, 4), 256, 0, stream>>>(ub, wrb, uhT);
    k_route_s<<<dim3(64, 10), 256, 0, stream>>>(uhT, bl, vv, out, 1, 0);
    k_route_b<<<dim3(64, 10), 256, 0, stream>>>(uhT, vv, bl, 1);
    k_route_s<<<dim3(64, 10), 256, 0, stream>>>(uhT, bl, vv, out, 0, 0);
    k_route_b<<<dim3(64, 10), 256, 0, stream>>>(uhT, vv, bl, 0);
    k_route_s<<<dim3(64, 10), 256, 0, stream>>>(uhT, bl, vv, out, 0, 1);
}

// Round 13
// 342.377 us; speedup vs baseline: 2.1101x; 1.0444x over previous
//
#include <hip/hip_runtime.h>
#include <hip/hip_bf16.h>
#include <math.h>

// ---------------------------------------------------------------------------
// GuoCapSAREncoder round 13: weights pre-packed into MFMA-FRAGMENT-READY
// layout (w2a / wca: [frag][lane][8] bf16) so A-loads are base + lane*16B --
// fully coalesced 16-line transactions instead of 32-line gathers (round 12's
// conv2 spent ~35% of its span on A-gather line touches; MfmaUtil 17%).
// Kernel structure/tiling/numerics frozen from round 12.
// ---------------------------------------------------------------------------

#define EPSF 1e-8f

typedef __bf16 bf16x8 __attribute__((ext_vector_type(8)));
typedef __bf16 bf16x4 __attribute__((ext_vector_type(4)));
typedef float floatx4 __attribute__((ext_vector_type(4)));
typedef float floatx16 __attribute__((ext_vector_type(16)));

// ---- weight transposes ----------------------------------------------------
__global__ __launch_bounds__(256) void k_t_w1b(const float* __restrict__ w1, __bf16* __restrict__ w1b) {
    int i = blockIdx.x * 256 + threadIdx.x;          // 12*128*8 = 12288
    if (i >= 12288) return;
    int kt = i >> 10, oc = (i >> 3) & 127, j = i & 7;
    int k = kt * 8 + j;
    w1b[i] = (__bf16)(k < 81 ? w1[oc * 81 + k] : 0.f);
}

// w2[oc64][ic128][khw25] -> w2a frag-ready: f = ((icc*25+khw)*4+ks)*2+mt,
// element [f][lane=h*32+c32][j] = w2[mt*32+c32][icc*64+ks*16+h*8+j][khw]
__global__ __launch_bounds__(256) void k_t_w2a(const float* __restrict__ w2, __bf16* __restrict__ w2a) {
    int i = blockIdx.x * 256 + threadIdx.x;          // 204800
    if (i >= 204800) return;
    int j = i & 7, lane = (i >> 3) & 63, f = i >> 9;
    int mt = f & 1, ks = (f >> 1) & 3, rem = f >> 3;
    int khw = rem % 25, icc = rem / 25;
    int c32 = lane & 31, h = lane >> 5;
    int oc = mt * 32 + c32;
    int ic = icc * 64 + ks * 16 + h * 8 + j;
    w2a[i] = (__bf16)w2[(oc * 128 + ic) * 25 + khw];
}

// wc[oc128][ic64][khw64] -> wca frag-ready: f = (((icc*64+khw)*2+ks)*4+ct,
// element [f][lane][j] = wc[ct*32+c32][icc*32+ks*16+h*8+j][khw]
__global__ __launch_bounds__(256) void k_t_wca(const float* __restrict__ wc, __bf16* __restrict__ wca) {
    int i = blockIdx.x * 256 + threadIdx.x;          // 524288
    if (i >= 524288) return;
    int j = i & 7, lane = (i >> 3) & 63, f = i >> 9;
    int ct = f & 3, ks = (f >> 2) & 1, khw = (f >> 3) & 63, icc = f >> 9;
    int c32 = lane & 31, h = lane >> 5;
    int oc = ct * 32 + c32;
    int ic = icc * 32 + ks * 16 + h * 8 + j;
    wca[i] = (__bf16)wc[(oc * 64 + ic) * 64 + khw];
}

__global__ __launch_bounds__(256) void k_t_wrb(const float* __restrict__ Wr, __bf16* __restrict__ wrb) {
    int i = blockIdx.x * 256 + threadIdx.x;          // 5242880
    if (i >= 5242880) return;
    wrb[i] = (__bf16)Wr[i];
}

// ---- conv1 9x9 + ReLU + maxpool2 via MFMA -> h1n NHWC bf16 [b][42][42][128]
__global__ __launch_bounds__(256, 3) void k_conv1_mfma(const float* __restrict__ x,
                                                       const __bf16* __restrict__ w1b,
                                                       const float* __restrict__ b1,
                                                       __bf16* __restrict__ h1n) {
    __shared__ float xs[960];                        // 10 rows x 92 fp32 (+pad)
    __shared__ __bf16 Bl[18432];                     // 12kt x 2row x 96pos x 8j
    int py = blockIdx.x, ocg = blockIdx.y, b = blockIdx.z;
    int t = threadIdx.x;
    int lane = t & 63, w = t >> 6;
    int cc = lane & 15, q = lane >> 4;

    const float* xb = x + (size_t)b * 8464 + 2 * py * 92;
    for (int j = t; j < 920; j += 256) xs[j] = xb[j];

    int ocA = ocg * 64 + w * 16 + cc;
    bf16x8 af[3];
#pragma unroll
    for (int ks = 0; ks < 3; ++ks)
        af[ks] = *(const bf16x8*)(w1b + ((ks * 4 + q) * 128 + ocA) * 8);

    __syncthreads();

    if (t < 192) {
        int row = t / 96, pos = t - (t / 96) * 96;
        int sbase = row * 92 + pos;
        bool pvalid = pos < 84;
#pragma unroll
        for (int kt = 0; kt < 12; ++kt) {
            bf16x8 pk;
#pragma unroll
            for (int j = 0; j < 8; ++j) {
                int k = kt * 8 + j;
                int kh = k / 9, kw = k - kh * 9;
                float v = (pvalid && k < 81) ? xs[sbase + kh * 92 + kw] : 0.f;
                pk[j] = (__bf16)v;
            }
            *(bf16x8*)(Bl + ((kt * 2 + row) * 96 + pos) * 8) = pk;
        }
    }
    __syncthreads();

    floatx4 acc[2][6];
    const char* Bb = (const char*)Bl + cc * 16 + q * 3072;
#pragma unroll
    for (int rr = 0; rr < 2; ++rr)
#pragma unroll
        for (int n6 = 0; n6 < 6; ++n6) {
            floatx4 a = (floatx4){0.f, 0.f, 0.f, 0.f};
#pragma unroll
            for (int ks = 0; ks < 3; ++ks) {
                bf16x8 bf = *(const bf16x8*)(Bb + ks * 12288 + rr * 1536 + n6 * 256);
                a = __builtin_amdgcn_mfma_f32_16x16x32_bf16(af[ks], bf, a, 0, 0, 0);
            }
            acc[rr][n6] = a;
        }

    int oc0 = ocg * 64 + w * 16 + q * 4;
    float4 bv = *(const float4*)(b1 + oc0);
    size_t obase = (((size_t)b * 42 + py) * 42) * 128 + oc0;
#pragma unroll
    for (int n6 = 0; n6 < 6; ++n6) {
        bf16x4 pk;
#pragma unroll
        for (int r = 0; r < 4; ++r) {
            float vert = fmaxf(acc[0][n6][r], acc[1][n6][r]);
            float hz = fmaxf(vert, __shfl_xor(vert, 1, 64));
            float pooled = fmaxf(hz + ((const float*)&bv)[r], 0.f);
            pk[r] = (__bf16)pooled;
        }
        if ((cc & 1) == 0) {
            int px = n6 * 8 + (cc >> 1);
            if (px < 42)
                *(bf16x4*)(h1n + obase + (size_t)px * 128) = pk;
        }
    }
}

// ---- conv2 5x5 via MFMA 32x32x16: h1n NHWC -> h2n NHWC bf16 [b][38][38][64]
// A-loads now frag-ready: w2a + frag*512 + lane*8 (fully coalesced).
__global__ __launch_bounds__(192, 2) void k_conv2(const __bf16* __restrict__ h1n,
                                                  const __bf16* __restrict__ w2a,
                                                  const float* __restrict__ b2,
                                                  __bf16* __restrict__ h2n) {
    __shared__ __bf16 ins[25704];                    // 378 pos * 136 B = 51408 B
    int g = blockIdx.x, b = blockIdx.y;              // g in [0,8)
    int row0 = g * 5;
    int t = threadIdx.x;
    int lane = t & 63, w = t >> 6;                   // w in [0,3)
    int c32 = lane & 31, h = lane >> 5;
    int validp = (g < 7) ? 190 : 114;

    int baseN[2], posi[2];
#pragma unroll
    for (int nt = 0; nt < 2; ++nt) {
        int pi = (w * 2 + nt) * 32 + c32;
        int pc = pi < validp ? pi : validp - 1;
        int r = pc / 38, c = pc - r * 38;
        posi[nt] = pi;
        baseN[nt] = (r * 42 + c) * 136 + h * 16;
    }
    floatx16 acc[2][2];
#pragma unroll
    for (int mt = 0; mt < 2; ++mt)
#pragma unroll
        for (int nt = 0; nt < 2; ++nt)
#pragma unroll
            for (int i = 0; i < 16; ++i) acc[mt][nt][i] = 0.f;

    for (int icc = 0; icc < 2; ++icc) {
        int ic0 = icc * 64;
        __syncthreads();
        for (int j = t; j < 3024; j += 192) {        // 9 rows x 42 x 8 sb
            int lr = j / 336, rem = j - lr * 336;
            int ix = rem >> 3, sb = rem & 7;
            int rg = row0 + lr; if (rg > 41) rg = 41;
            const uint4* src = (const uint4*)(h1n + ((((size_t)b * 42 + rg) * 42 + ix) * 128 + ic0 + sb * 8));
            int pos = lr * 42 + ix;
            *(uint4*)((char*)ins + (size_t)pos * 136 + sb * 16) = *src;
        }
        __syncthreads();
        const __bf16* wic = w2a + (size_t)icc * 25 * 4096 + (lane << 3);
#pragma unroll
        for (int khw = 0; khw < 25; ++khw) {
            int kh = khw / 5, kw = khw - kh * 5;
            int doff = (kh * 42 + kw) * 136;
            const __bf16* wk = wic + khw * 4096;     // 4 ks x 2 mt x 512
#pragma unroll
            for (int ks = 0; ks < 4; ++ks) {
                bf16x8 a0 = *(const bf16x8*)(wk + ks * 1024);
                bf16x8 a1 = *(const bf16x8*)(wk + ks * 1024 + 512);
#pragma unroll
                for (int nt = 0; nt < 2; ++nt) {
                    bf16x8 bfr = *(const bf16x8*)((char*)ins + baseN[nt] + doff + ks * 32);
                    acc[0][nt] = __builtin_amdgcn_mfma_f32_32x32x16_bf16(a0, bfr, acc[0][nt], 0, 0, 0);
                    acc[1][nt] = __builtin_amdgcn_mfma_f32_32x32x16_bf16(a1, bfr, acc[1][nt], 0, 0, 0);
                }
            }
        }
    }
#pragma unroll
    for (int nt = 0; nt < 2; ++nt) {
        int pi = posi[nt];
        if (pi < validp) {
            int r = pi / 38, c = pi - r * 38;
            int oh = row0 + r;
            size_t obase = (((size_t)b * 38 + oh) * 38 + c) * 64;
#pragma unroll
            for (int mt = 0; mt < 2; ++mt) {
#pragma unroll
                for (int g2 = 0; g2 < 4; ++g2) {
                    int oc0 = mt * 32 + g2 * 8 + h * 4;
                    float4 bv = *(const float4*)(b2 + oc0);
                    bf16x4 pk;
                    pk.x = (__bf16)(acc[mt][nt][g2 * 4 + 0] + bv.x);
                    pk.y = (__bf16)(acc[mt][nt][g2 * 4 + 1] + bv.y);
                    pk.z = (__bf16)(acc[mt][nt][g2 * 4 + 2] + bv.z);
                    pk.w = (__bf16)(acc[mt][nt][g2 * 4 + 3] + bv.w);
                    *(bf16x4*)(h2n + obase + oc0) = pk;
                }
            }
        }
    }
}

// ---- caps conv 8x8 s2 via MFMA 32x32x16 + FUSED squash -> ub bf16 ---------
// A-loads frag-ready: wca + frag*512 + lane*8 (fully coalesced).
__global__ __launch_bounds__(256, 4) void k_convcaps(const __bf16* __restrict__ h2n,
                                                     const __bf16* __restrict__ wca,
                                                     const float* __restrict__ bc,
                                                     __bf16* __restrict__ ub) {
    __shared__ __bf16 ins[13680];                    // 380 * 72 B = 27360 B
    int g = blockIdx.x, b = blockIdx.y;              // g in [0,8)
    int t = threadIdx.x;
    int lane = t & 63, ct = t >> 6;                  // wave = capsule type
    int c32 = lane & 31, h = lane >> 5;
    int rloc = c32 >> 4, cx = c32 & 15;

    floatx16 acc;
#pragma unroll
    for (int i = 0; i < 16; ++i) acc[i] = 0.f;

    int Bbase = (76 * rloc + cx) * 72 + h * 16;      // lane byte base in slab
    for (int icc = 0; icc < 2; ++icc) {
        int ic0 = icc * 32;
        __syncthreads();
        for (int j = t; j < 1520; j += 256) {        // 10 rows x 38 cols x 4 s
            int r = j / 152, rem = j - r * 152;
            int c = rem >> 2, s = rem & 3;
            const uint4* src = (const uint4*)(h2n + ((((size_t)b * 38 + 4 * g + r) * 38 + c) * 64 + ic0 + s * 8));
            int X = (r * 2 + (c & 1)) * 19 + (c >> 1);
            *(uint4*)((char*)ins + X * 72 + s * 16) = *src;
        }
        __syncthreads();
        const __bf16* wic = wca + ((size_t)icc * 64 * 8 + ct) * 512 + (lane << 3);
#pragma unroll
        for (int khw = 0; khw < 64; ++khw) {
            int kh = khw >> 3, kw = khw & 7;
            int par = kw & 1, k2 = kw >> 1;
            int doff = ((kh * 2 + par) * 19 + k2) * 72;
            const __bf16* wk = wic + khw * 4096;     // 2 ks x 4 ct x 512
#pragma unroll
            for (int ks = 0; ks < 2; ++ks) {
                bf16x8 af = *(const bf16x8*)(wk + ks * 2048);
                bf16x8 bfr = *(const bf16x8*)((char*)ins + Bbase + doff + ks * 32);
                acc = __builtin_amdgcn_mfma_f32_32x32x16_bf16(af, bfr, acc, 0, 0, 0);
            }
        }
    }
    // fused bias + squash
    float vals[16];
    float n2p = 0.f;
#pragma unroll
    for (int g2 = 0; g2 < 4; ++g2) {
        float4 bv = *(const float4*)(bc + ct * 32 + g2 * 8 + h * 4);
#pragma unroll
        for (int j = 0; j < 4; ++j) {
            float v = acc[g2 * 4 + j] + ((const float*)&bv)[j];
            vals[g2 * 4 + j] = v;
            n2p = fmaf(v, v, n2p);
        }
    }
    float n2 = n2p + __shfl_xor(n2p, 32, 64);
    float scale = (n2 / (1.f + n2)) / sqrtf(n2 + EPSF);
    int pos = (2 * g + rloc) * 16 + cx;              // y*16 + x
    __bf16* dst = ub + (((size_t)b * 1024 + ct * 256 + pos) * 32);
#pragma unroll
    for (int g2 = 0; g2 < 4; ++g2) {
        bf16x4 pk;
        pk.x = (__bf16)(vals[g2 * 4 + 0] * scale);
        pk.y = (__bf16)(vals[g2 * 4 + 1] * scale);
        pk.z = (__bf16)(vals[g2 * 4 + 2] * scale);
        pk.w = (__bf16)(vals[g2 * 4 + 3] * scale);
        *(bf16x4*)(dst + g2 * 8 + h * 4) = pk;
    }
}

// ---- u_hat: ub bf16 [64,1024,32] x wrb bf16 [1024,10,16,32] -> uhT bf16 ---
__global__ __launch_bounds__(256, 2) void k_uhat(const __bf16* __restrict__ ub,
                                                 const __bf16* __restrict__ wrb,
                                                 __bf16* __restrict__ uhT) {
    int pt = blockIdx.x, ts = blockIdx.y, bz = blockIdx.z;
    int t = threadIdx.x;
    int p = pt * 64 + (t & 63);
    int q = t >> 6;
    bf16x8 wf[4][4];
#pragma unroll
    for (int o4 = 0; o4 < 4; ++o4)
#pragma unroll
        for (int j = 0; j < 4; ++j)
            wf[o4][j] = *(const bf16x8*)(wrb + (((size_t)p * 10 + ts) * 16 + q * 4 + o4) * 32 + j * 8);
#pragma unroll 1
    for (int bi = 0; bi < 16; ++bi) {
        int b = bz * 16 + bi;
        bf16x8 uf[4];
        const bf16x8* up = (const bf16x8*)(ub + ((size_t)b * 1024 + p) * 32);
#pragma unroll
        for (int j = 0; j < 4; ++j) uf[j] = up[j];
#pragma unroll
        for (int o4 = 0; o4 < 4; ++o4) {
            float s = 0.f;
#pragma unroll
            for (int j = 0; j < 4; ++j)
#pragma unroll
                for (int e = 0; e < 8; ++e)
                    s = fmaf((float)uf[j][e], (float)wf[o4][j][e], s);
            uhT[(((size_t)b * 10 + ts) * 16 + q * 4 + o4) * 1024 + p] = (__bf16)s;
        }
    }
}

// ---- routing: s = sum_p softmax(bl)_pt * u_hat ; v = squash(s) ------------
__global__ __launch_bounds__(256) void k_route_s(const __bf16* __restrict__ uhT,
                                                 const float* __restrict__ bl,
                                                 float* __restrict__ vout,
                                                 float* __restrict__ out,
                                                 int first, int last) {
    __shared__ float sred[4][16];
    int b = blockIdx.x, tt = blockIdx.y;
    int t = threadIdx.x;
    float acc[16];
#pragma unroll
    for (int o = 0; o < 16; ++o) acc[o] = 0.f;
    const float* blb = bl + b * 10240;
    const __bf16* uhb = uhT + ((size_t)b * 10 + tt) * 16384;
    for (int p = t; p < 1024; p += 256) {
        float c;
        if (first) {
            c = 0.1f;
        } else {
            float den = 0.f, et = 0.f;
#pragma unroll
            for (int tp = 0; tp < 10; ++tp) {
                float e = expf(blb[tp * 1024 + p]);
                den += e;
                if (tp == tt) et = e;
            }
            c = et / den;
        }
#pragma unroll
        for (int o = 0; o < 16; ++o)
            acc[o] = fmaf(c, (float)uhb[o * 1024 + p], acc[o]);
    }
    int lane = t & 63, wid = t >> 6;
#pragma unroll
    for (int o = 0; o < 16; ++o) {
        float v = acc[o];
#pragma unroll
        for (int off = 32; off >= 1; off >>= 1) v += __shfl_xor(v, off, 64);
        if (lane == 0) sred[wid][o] = v;
    }
    __syncthreads();
    if (t < 16) {
        float s = (sred[0][t] + sred[1][t]) + (sred[2][t] + sred[3][t]);
        float n2 = s * s;
#pragma unroll
        for (int off = 1; off < 16; off <<= 1) n2 += __shfl_xor(n2, off, 16);
        float scale = (n2 / (1.f + n2)) / sqrtf(n2 + EPSF);
        vout[(b * 10 + tt) * 16 + t] = s * scale;
        if (last && t == 0) {
            float sv2 = n2 * scale * scale;
            out[b * 10 + tt] = sqrtf(sv2 + EPSF);
        }
    }
}

// ---- routing: bl (+)= sum_o u_hat * v -------------------------------------
__global__ __launch_bounds__(256) void k_route_b(const __bf16* __restrict__ uhT,
                                                 const float* __restrict__ vv,
                                                 float* __restrict__ bl,
                                                 int first) {
    __shared__ float vs[16];
    int b = blockIdx.x, tt = blockIdx.y;
    int t = threadIdx.x;
    if (t < 16) vs[t] = vv[(b * 10 + tt) * 16 + t];
    __syncthreads();
    const __bf16* uhb = uhT + ((size_t)b * 10 + tt) * 16384;
    float* blb = bl + (b * 10 + tt) * 1024;
    for (int p = t; p < 1024; p += 256) {
        float d = 0.f;
#pragma unroll
        for (int o = 0; o < 16; ++o) d = fmaf((float)uhb[o * 1024 + p], vs[o], d);
        blb[p] = first ? d : (blb[p] + d);
    }
}

// ---------------------------------------------------------------------------
extern "C" void kernel_launch(void* const* d_in, const int* in_sizes, int n_in,
                              void* d_out, int out_size, void* d_ws, size_t ws_size,
                              hipStream_t stream) {
    const float* x  = (const float*)d_in[0];
    const float* w1 = (const float*)d_in[1];
    const float* b1 = (const float*)d_in[2];
    const float* w2 = (const float*)d_in[3];
    const float* b2 = (const float*)d_in[4];
    const float* wc = (const float*)d_in[5];
    const float* bc = (const float*)d_in[6];
    const float* Wr = (const float*)d_in[7];
    float* out = (float*)d_out;
    float* ws  = (float*)d_ws;

    // workspace layout (float offsets)
    __bf16* w2a = (__bf16*)(ws);                  // 204800 bf16
    __bf16* wca = (__bf16*)(ws + 102400);         // 524288 bf16
    __bf16* w1b = (__bf16*)(ws + 364544);         // 12288 bf16
    __bf16* h1n = (__bf16*)(ws + 375040);         // 14450688 bf16
    __bf16* h2n = (__bf16*)(ws + 7600384);        // 5914624 bf16
    __bf16* ub  = (__bf16*)(ws + 12654848);       // 2097152 bf16
    float*  bl  = ws + 14752000;                  // 655360 f
    float*  vv  = ws + 15407360;                  // 10240 f
    __bf16* wrb = (__bf16*)(ws + 15417600);       // 5242880 bf16
    __bf16* uhT = (__bf16*)(ws + 375040);         // overlays h1n (dead by k_uhat)

    k_t_w1b<<<48, 256, 0, stream>>>(w1, w1b);
    k_t_w2a<<<800, 256, 0, stream>>>(w2, w2a);
    k_t_wca<<<2048, 256, 0, stream>>>(wc, wca);
    k_t_wrb<<<20480, 256, 0, stream>>>(Wr, wrb);
    k_conv1_mfma<<<dim3(42, 2, 64), 256, 0, stream>>>(x, w1b, b1, h1n);
    k_conv2<<<dim3(8, 64), 192, 0, stream>>>(h1n, w2a, b2, h2n);
    k_convcaps<<<dim3(8, 64), 256, 0, stream>>>(h2n, wca, bc, ub);
    k_uhat<<<dim3(16, 10, 4), 256, 0, stream>>>(ub, wrb, uhT);
    k_route_s<<<dim3(64, 10), 256, 0, stream>>>(uhT, bl, vv, out, 1, 0);
    k_route_b<<<dim3(64, 10), 256, 0, stream>>>(uhT, vv, bl, 1);
    k_route_s<<<dim3(64, 10), 256, 0, stream>>>(uhT, bl, vv, out, 0, 0);
    k_route_b<<<dim3(64, 10), 256, 0, stream>>>(uhT, vv, bl, 0);
    k_route_s<<<dim3(64, 10), 256, 0, stream>>>(uhT, bl, vv, out, 0, 1);
}